// Round 2
// baseline (1923.622 us; speedup 1.0000x reference)
//
#include <hip/hip_runtime.h>
#include <math.h>

// Problem constants (fixed shapes from setup_inputs)
constexpr int B_  = 2;
constexpr int L_  = 512;    // txt tokens
constexpr int N_  = 2048;   // img tokens (H=64, W=32)
constexpr int T_  = 2560;   // L_+N_
constexpr int D_  = 512;
constexpr int NH_ = 4;
constexpr int HD_ = 128;
constexpr int FF_ = 2048;
constexpr int SIXD = 3072;
#define SCALE_ 0.08838834764831843f

// Workspace layout (floats). Total = 18,378,768 floats = 73.5 MB.
constexpr size_t QSZ    = (size_t)B_ * NH_ * T_ * HD_;      // 2,621,440 (== B*T*D)
constexpr size_t O_ETXT = 0;
constexpr size_t O_EIMG = O_ETXT + (size_t)B_ * SIXD;       // 6144
constexpr size_t O_MOD  = O_EIMG + (size_t)B_ * SIXD;       // 12288
constexpr size_t O_EFF  = O_MOD + (size_t)B_ * NH_ * N_;    // 28672
constexpr size_t O_XN   = O_EFF + 16;                        // 28688
constexpr size_t O_Q    = O_XN + QSZ;
constexpr size_t O_K    = O_Q + QSZ;
constexpr size_t O_V    = O_K + QSZ;
constexpr size_t O_ATTN = O_V + QSZ;
constexpr size_t O_X2   = O_ATTN + QSZ;
constexpr size_t O_XIN2 = O_X2 + QSZ;
constexpr size_t O_H    = O_Q;   // reuse Q..ATTN region (10,485,760 floats) for MLP hidden

// ---------------- adaLN: e = silu(vec) @ W.T + b  (both streams) ----------------
__global__ __launch_bounds__(256) void k_adaln(const float* __restrict__ vec,
                                               const float* __restrict__ wt, const float* __restrict__ bt,
                                               const float* __restrict__ wi, const float* __restrict__ bi,
                                               float* __restrict__ ws) {
  // grid = 2 streams * B * (3072/256) = 48
  int blk = blockIdx.x;
  int s = blk / (B_ * 12);
  int rem = blk % (B_ * 12);
  int b = rem / 12;
  int o = (rem % 12) * 256 + threadIdx.x;
  __shared__ float sv[D_];
  for (int i = threadIdx.x; i < D_; i += 256) {
    float x = vec[b * D_ + i];
    sv[i] = x / (1.0f + __expf(-x));
  }
  __syncthreads();
  const float* w = (s == 0) ? wt : wi;
  const float* bb = (s == 0) ? bt : bi;
  const float4* wrow = (const float4*)(w + (size_t)o * D_);
  float acc = 0.f;
  for (int d4 = 0; d4 < D_ / 4; ++d4) {
    float4 wv = wrow[d4];
    int d = d4 * 4;
    acc += wv.x * sv[d] + wv.y * sv[d + 1] + wv.z * sv[d + 2] + wv.w * sv[d + 3];
  }
  acc += bb[o];
  float* e = ws + ((s == 0) ? O_ETXT : O_EIMG);
  e[b * SIXD + o] = acc;
}

// ---------------- mod (bilinear upsample + affine + clip + exp) and eff ----------------
__global__ __launch_bounds__(256) void k_mod(const float* __restrict__ sspat,
                                             const float* __restrict__ mw, const float* __restrict__ mb,
                                             const float* __restrict__ stemp,
                                             float* __restrict__ ws) {
  int idx = blockIdx.x * 256 + threadIdx.x;  // B*NH*N = 16384
  if (idx < B_) {
    float s = 0.f;
    for (int h = 0; h < NH_; ++h) s += stemp[idx * NH_ + h];
    float t = fmaxf(s * 0.25f, 0.1f);
    ws[O_EFF + idx] = SCALE_ / t;
  }
  int b = idx / (NH_ * N_);
  int h = (idx / N_) % NH_;
  int n = idx % N_;
  int y = n >> 5;      // W=32
  int x = n & 31;
  // jax.image.resize bilinear, half-pixel centers, edge clamp. 8->64 (y), 8->32 (x)
  float fy = (y + 0.5f) * 0.125f - 0.5f;
  float fx = (x + 0.5f) * 0.25f  - 0.5f;
  float y0f = floorf(fy), x0f = floorf(fx);
  float wy = fy - y0f, wx = fx - x0f;
  int y0 = (int)y0f, x0 = (int)x0f;
  int iy0 = y0 < 0 ? 0 : y0, iy1 = (y0 + 1) > 7 ? 7 : (y0 + 1);
  int ix0 = x0 < 0 ? 0 : x0, ix1 = (x0 + 1) > 7 ? 7 : (x0 + 1);
  const float* S = sspat + b * 64;
  float v00 = S[iy0*8+ix0], v01 = S[iy0*8+ix1];
  float v10 = S[iy1*8+ix0], v11 = S[iy1*8+ix1];
  float up = (1.f-wy)*((1.f-wx)*v00 + wx*v01) + wy*((1.f-wx)*v10 + wx*v11);
  float m = up * mw[h] + mb[h];
  m = fminf(fmaxf(m, -2.f), 2.f);
  ws[O_MOD + idx] = __expf(m);
}

// ---------------- rms + adaLN modulate: out = rms(x,w)*(1+sc)+sh ----------------
template<bool FROM_INPUT>
__global__ __launch_bounds__(256) void k_rmsmod(const float* __restrict__ txt, const float* __restrict__ img,
                                                const float* __restrict__ src_ws,
                                                const float* __restrict__ nw_txt, const float* __restrict__ nw_img,
                                                int sh_off, int sc_off,
                                                const float* __restrict__ e_ws,
                                                float* __restrict__ out) {
  int row = blockIdx.x;         // B*T rows
  int b = row / T_;
  int t = row % T_;
  bool is_txt = t < L_;
  int i0 = threadIdx.x * 2;
  float x0, x1;
  if (FROM_INPUT) {
    const float* src = is_txt ? (txt + ((size_t)b * L_ + t) * D_)
                              : (img + ((size_t)b * N_ + (t - L_)) * D_);
    x0 = src[i0]; x1 = src[i0 + 1];
  } else {
    const float* src = src_ws + (size_t)row * D_;
    x0 = src[i0]; x1 = src[i0 + 1];
  }
  float ss = x0 * x0 + x1 * x1;
  for (int off = 32; off; off >>= 1) ss += __shfl_down(ss, off, 64);
  __shared__ float red[4];
  if ((threadIdx.x & 63) == 0) red[threadIdx.x >> 6] = ss;
  __syncthreads();
  float tot = red[0] + red[1] + red[2] + red[3];
  float r = rsqrtf(tot * (1.0f / D_) + 1e-6f);
  const float* e = e_ws + (is_txt ? O_ETXT : O_EIMG) + (size_t)b * SIXD;
  const float* nw = is_txt ? nw_txt : nw_img;
  float* o = out + (size_t)row * D_;
  o[i0]     = x0 * r * nw[i0]     * (1.f + e[sc_off + i0])     + e[sh_off + i0];
  o[i0 + 1] = x1 * r * nw[i0 + 1] * (1.f + e[sc_off + i0 + 1]) + e[sh_off + i0 + 1];
}

// ---------------- shared GEMM core: 16 rows (LDS, broadcast) x 1 col/thread ----------------
// n8 = number of 8-float groups along K. xs rows are 512 floats apart.
__device__ __forceinline__ void gemm16(const float* xs, const float4* wrow, float* acc, int n8) {
  const float4* xs4 = (const float4*)xs;
  for (int d8 = 0; d8 < n8; ++d8) {
    float4 wa = wrow[d8 * 2];
    float4 wb = wrow[d8 * 2 + 1];
    #pragma unroll
    for (int r = 0; r < 16; ++r) {
      float4 a = xs4[r * 128 + d8 * 2];
      float4 c = xs4[r * 128 + d8 * 2 + 1];
      acc[r] += wa.x*a.x + wa.y*a.y + wa.z*a.z + wa.w*a.w
              + wb.x*c.x + wb.y*c.y + wb.z*c.z + wb.w*c.w;
    }
  }
}

// ---------------- QKV projection ----------------
__global__ __launch_bounds__(256) void k_qkv(const float* __restrict__ ws_ro, float* __restrict__ wsw,
                                             const float* __restrict__ wq_txt, const float* __restrict__ wq_img) {
  // grid = (B*T/16) * 6
  int rb = blockIdx.x / 6, jc = blockIdx.x % 6;
  int row0 = rb * 16;
  int b = row0 / T_, t0 = row0 % T_;
  bool is_txt = t0 < L_;
  __shared__ __align__(16) float xs[16 * D_];
  const float4* src4 = (const float4*)(ws_ro + O_XN + (size_t)row0 * D_);
  float4* xs4w = (float4*)xs;
  for (int i = threadIdx.x; i < 16 * D_ / 4; i += 256) xs4w[i] = src4[i];
  __syncthreads();
  int j = jc * 256 + threadIdx.x;  // 0..1535
  const float* w = is_txt ? wq_txt : wq_img;
  float acc[16];
  #pragma unroll
  for (int r = 0; r < 16; ++r) acc[r] = 0.f;
  gemm16(xs, (const float4*)(w + (size_t)j * D_), acc, D_ / 8);
  int which = j >> 9;
  int h = (j & 511) >> 7;
  int dd = j & 127;
  float* dst = wsw + (which == 0 ? O_Q : which == 1 ? O_K : O_V)
             + (((size_t)b * NH_ + h) * T_ + t0) * HD_ + dd;
  #pragma unroll
  for (int r = 0; r < 16; ++r) dst[(size_t)r * HD_] = acc[r];
}

// ---------------- RoPE + mod on img Q,K (in place) ----------------
__global__ __launch_bounds__(256) void k_ropemod(float* __restrict__ wsw, const float* __restrict__ rope) {
  int idx = blockIdx.x * 256 + threadIdx.x;  // B*NH*N*64 = 1,048,576
  int i = idx & 63;
  int p = idx >> 6;
  int n = p & (N_ - 1);
  int bh = p >> 11;            // b*NH+h
  float c = rope[(size_t)n * HD_ + 2 * i];
  float s = rope[(size_t)n * HD_ + 2 * i + 1];
  float m = wsw[O_MOD + (size_t)bh * N_ + n];
  size_t base = ((size_t)bh * T_ + (L_ + n)) * HD_ + 2 * i;
  float* Q = wsw + O_Q;
  float* K = wsw + O_K;
  float q0 = Q[base], q1 = Q[base + 1];
  Q[base]     = (q0 * c - q1 * s) * m;
  Q[base + 1] = (q1 * c + q0 * s) * m;
  float k0 = K[base], k1 = K[base + 1];
  K[base]     = (k0 * c - k1 * s) * m;
  K[base + 1] = (k1 * c + k0 * s) * m;
}

// ---------------- attention: 32x32 flash tiles, online softmax, O in registers ----------------
__global__ __launch_bounds__(256) void k_attn(const float* __restrict__ ws_ro, float* __restrict__ wsw) {
  // grid = B*NH*(T/32) = 640
  int nqt = T_ / 32;
  int qt = blockIdx.x % nqt;
  int bh = blockIdx.x / nqt;
  int b = bh >> 2, h = bh & 3;
  int q0row = qt * 32;
  float scale = (q0row < L_) ? SCALE_ : ws_ro[O_EFF + b];

  const float* Qb = ws_ro + O_Q + ((size_t)bh * T_ + q0row) * HD_;
  const float* Kb = ws_ro + O_K + (size_t)bh * T_ * HD_;
  const float* Vb = ws_ro + O_V + (size_t)bh * T_ * HD_;

  __shared__ __align__(16) float qs[32][132];
  __shared__ __align__(16) float ks[32][132];
  __shared__ __align__(16) float vs[32][132];
  __shared__ float ss[32][33];
  __shared__ float ms[32], ls[32], als[32];

  const float4* Q4 = (const float4*)Qb;
  for (int i = threadIdx.x; i < 32 * 32; i += 256) {
    int r = i >> 5, d4 = i & 31;
    float4 v = Q4[i];
    ((float4*)&qs[r][0])[d4] = make_float4(v.x * scale, v.y * scale, v.z * scale, v.w * scale);
  }
  if (threadIdx.x < 32) { ms[threadIdx.x] = -1e30f; ls[threadIdx.x] = 0.f; }
  __syncthreads();

  int qi0 = threadIdx.x >> 4;   // 0..15  (S-phase)
  int kj0 = threadIdx.x & 15;   // 0..15
  int oqi = threadIdx.x >> 3;   // 0..31  (O-phase)
  int odc = threadIdx.x & 7;    // 0..7 -> f4 idx {odc, odc+8, odc+16, odc+24}

  float4 o0 = make_float4(0,0,0,0), o1 = o0, o2 = o0, o3 = o0;

  for (int kt = 0; kt < T_ / 32; ++kt) {
    const float4* K4 = (const float4*)(Kb + (size_t)kt * 32 * HD_);
    const float4* V4 = (const float4*)(Vb + (size_t)kt * 32 * HD_);
    for (int i = threadIdx.x; i < 32 * 32; i += 256) {
      int r = i >> 5, d4 = i & 31;
      ((float4*)&ks[r][0])[d4] = K4[i];
      ((float4*)&vs[r][0])[d4] = V4[i];
    }
    __syncthreads();

    {
      const float4* qa = (const float4*)&qs[qi0][0];
      const float4* qb = (const float4*)&qs[qi0 + 16][0];
      const float4* ka = (const float4*)&ks[kj0][0];
      const float4* kb = (const float4*)&ks[kj0 + 16][0];
      float a00 = 0.f, a01 = 0.f, a10 = 0.f, a11 = 0.f;
      #pragma unroll 8
      for (int d4 = 0; d4 < 32; ++d4) {
        float4 x0 = qa[d4], x1 = qb[d4], y0 = ka[d4], y1 = kb[d4];
        a00 += x0.x*y0.x + x0.y*y0.y + x0.z*y0.z + x0.w*y0.w;
        a01 += x0.x*y1.x + x0.y*y1.y + x0.z*y1.z + x0.w*y1.w;
        a10 += x1.x*y0.x + x1.y*y0.y + x1.z*y0.z + x1.w*y0.w;
        a11 += x1.x*y1.x + x1.y*y1.y + x1.z*y1.z + x1.w*y1.w;
      }
      ss[qi0][kj0] = a00;      ss[qi0][kj0 + 16] = a01;
      ss[qi0 + 16][kj0] = a10; ss[qi0 + 16][kj0 + 16] = a11;
    }
    __syncthreads();

    if (threadIdx.x < 32) {
      int r = threadIdx.x;
      float mx = ms[r];
      #pragma unroll
      for (int j2 = 0; j2 < 32; ++j2) mx = fmaxf(mx, ss[r][j2]);
      float al = __expf(ms[r] - mx);
      float sum = 0.f;
      #pragma unroll
      for (int j2 = 0; j2 < 32; ++j2) { float pp = __expf(ss[r][j2] - mx); ss[r][j2] = pp; sum += pp; }
      ms[r] = mx; ls[r] = ls[r] * al + sum; als[r] = al;
    }
    __syncthreads();

    {
      float al = als[oqi];
      o0.x*=al; o0.y*=al; o0.z*=al; o0.w*=al;
      o1.x*=al; o1.y*=al; o1.z*=al; o1.w*=al;
      o2.x*=al; o2.y*=al; o2.z*=al; o2.w*=al;
      o3.x*=al; o3.y*=al; o3.z*=al; o3.w*=al;
      const float* prow = &ss[oqi][0];
      #pragma unroll 4
      for (int j2 = 0; j2 < 32; ++j2) {
        float pp = prow[j2];
        const float4* vrow = (const float4*)&vs[j2][0];
        float4 v0 = vrow[odc], v1 = vrow[odc + 8], v2 = vrow[odc + 16], v3 = vrow[odc + 24];
        o0.x += pp*v0.x; o0.y += pp*v0.y; o0.z += pp*v0.z; o0.w += pp*v0.w;
        o1.x += pp*v1.x; o1.y += pp*v1.y; o1.z += pp*v1.z; o1.w += pp*v1.w;
        o2.x += pp*v2.x; o2.y += pp*v2.y; o2.z += pp*v2.z; o2.w += pp*v2.w;
        o3.x += pp*v3.x; o3.y += pp*v3.y; o3.z += pp*v3.z; o3.w += pp*v3.w;
      }
    }
    __syncthreads();
  }

  float inv = 1.0f / ls[oqi];
  int t = q0row + oqi;
  float4* dst = (float4*)(wsw + O_ATTN + ((size_t)b * T_ + t) * D_ + h * HD_);
  dst[odc]      = make_float4(o0.x*inv, o0.y*inv, o0.z*inv, o0.w*inv);
  dst[odc + 8]  = make_float4(o1.x*inv, o1.y*inv, o1.z*inv, o1.w*inv);
  dst[odc + 16] = make_float4(o2.x*inv, o2.y*inv, o2.z*inv, o2.w*inv);
  dst[odc + 24] = make_float4(o3.x*inv, o3.y*inv, o3.z*inv, o3.w*inv);
}

// ---------------- out projection + gate + residual ----------------
__global__ __launch_bounds__(256) void k_proj(const float* __restrict__ ws_ro, float* __restrict__ wsw,
                                              const float* __restrict__ txt, const float* __restrict__ img,
                                              const float* __restrict__ w_txt, const float* __restrict__ w_img) {
  // grid = (B*T/16) * 2
  int rb = blockIdx.x >> 1, jc = blockIdx.x & 1;
  int row0 = rb * 16;
  int b = row0 / T_, t0 = row0 % T_;
  bool is_txt = t0 < L_;
  __shared__ __align__(16) float xs[16 * D_];
  const float4* src4 = (const float4*)(ws_ro + O_ATTN + (size_t)row0 * D_);
  float4* xs4w = (float4*)xs;
  for (int i = threadIdx.x; i < 16 * D_ / 4; i += 256) xs4w[i] = src4[i];
  __syncthreads();
  int j = jc * 256 + threadIdx.x;
  const float* w = is_txt ? w_txt : w_img;
  float acc[16];
  #pragma unroll
  for (int r = 0; r < 16; ++r) acc[r] = 0.f;
  gemm16(xs, (const float4*)(w + (size_t)j * D_), acc, D_ / 8);
  const float* e = ws_ro + (is_txt ? O_ETXT : O_EIMG) + (size_t)b * SIXD;
  float g = e[1024 + j];
  float* x2 = wsw + O_X2;
  #pragma unroll
  for (int r = 0; r < 16; ++r) {
    int t = t0 + r;
    float xin = is_txt ? txt[((size_t)b * L_ + t) * D_ + j]
                       : img[((size_t)b * N_ + (t - L_)) * D_ + j];
    x2[(size_t)(row0 + r) * D_ + j] = xin + g * acc[r];
  }
}

// ---------------- fc1 + gelu(tanh) ----------------
__global__ __launch_bounds__(256) void k_fc1(const float* __restrict__ ws_ro, float* __restrict__ wsw,
                                             const float* __restrict__ wt, const float* __restrict__ bt,
                                             const float* __restrict__ wi, const float* __restrict__ bi) {
  // grid = (B*T/16) * 8
  int rb = blockIdx.x >> 3, jc = blockIdx.x & 7;
  int row0 = rb * 16;
  int t0 = row0 % T_;
  bool is_txt = t0 < L_;
  __shared__ __align__(16) float xs[16 * D_];
  const float4* src4 = (const float4*)(ws_ro + O_XIN2 + (size_t)row0 * D_);
  float4* xs4w = (float4*)xs;
  for (int i = threadIdx.x; i < 16 * D_ / 4; i += 256) xs4w[i] = src4[i];
  __syncthreads();
  int j = jc * 256 + threadIdx.x;  // 0..2047
  const float* w = is_txt ? wt : wi;
  const float* bb = is_txt ? bt : bi;
  float acc[16];
  #pragma unroll
  for (int r = 0; r < 16; ++r) acc[r] = 0.f;
  gemm16(xs, (const float4*)(w + (size_t)j * D_), acc, D_ / 8);
  float bias = bb[j];
  #pragma unroll
  for (int r = 0; r < 16; ++r) {
    float x = acc[r] + bias;
    float th = tanhf(0.7978845608028654f * (x + 0.044715f * x * x * x));
    wsw[O_H + (size_t)(row0 + r) * FF_ + j] = 0.5f * x * (1.f + th);
  }
}

// ---------------- fc2 + gate + residual -> f32 out ----------------
__global__ __launch_bounds__(256) void k_fc2(const float* __restrict__ ws_ro, float* __restrict__ out,
                                             const float* __restrict__ wt, const float* __restrict__ bt,
                                             const float* __restrict__ wi, const float* __restrict__ bi) {
  // grid = (B*T/16) * 2 ; K=2048 staged in 4 chunks of 512
  int rb = blockIdx.x >> 1, jc = blockIdx.x & 1;
  int row0 = rb * 16;
  int b = row0 / T_, t0 = row0 % T_;
  bool is_txt = t0 < L_;
  __shared__ __align__(16) float xs[16 * D_];
  float4* xs4w = (float4*)xs;
  int j = jc * 256 + threadIdx.x;  // 0..511
  const float* w = is_txt ? wt : wi;
  const float* bb = is_txt ? bt : bi;
  float acc[16];
  #pragma unroll
  for (int r = 0; r < 16; ++r) acc[r] = 0.f;
  for (int kc = 0; kc < 4; ++kc) {
    __syncthreads();
    const float* hsrc = ws_ro + O_H + (size_t)row0 * FF_ + kc * 512;
    for (int i = threadIdx.x; i < 16 * 512 / 4; i += 256) {
      int r = i >> 7, d4 = i & 127;
      xs4w[i] = ((const float4*)(hsrc + (size_t)r * FF_))[d4];
    }
    __syncthreads();
    gemm16(xs, (const float4*)(w + (size_t)j * FF_ + kc * 512), acc, 64);
  }
  float bias = bb[j];
  const float* e = ws_ro + (is_txt ? O_ETXT : O_EIMG) + (size_t)b * SIXD;
  float g = e[2560 + j];
  #pragma unroll
  for (int r = 0; r < 16; ++r) {
    int t = t0 + r;
    float res = ws_ro[O_X2 + (size_t)(row0 + r) * D_ + j];
    float val = res + g * (acc[r] + bias);
    size_t o = is_txt ? ((size_t)b * L_ + t) * D_ + j
                      : (size_t)B_ * L_ * D_ + ((size_t)b * N_ + (t - L_)) * D_ + j;
    out[o] = val;
  }
}

extern "C" void kernel_launch(void* const* d_in, const int* in_sizes, int n_in,
                              void* d_out, int out_size, void* d_ws, size_t ws_size,
                              hipStream_t stream) {
  (void)in_sizes; (void)n_in; (void)out_size; (void)ws_size;
  const float* txt    = (const float*)d_in[0];
  const float* img    = (const float*)d_in[1];
  const float* vec    = (const float*)d_in[2];
  const float* rope   = (const float*)d_in[3];
  const float* stemp  = (const float*)d_in[4];
  const float* sspat  = (const float*)d_in[5];
  const float* i_aw   = (const float*)d_in[6];
  const float* i_ab   = (const float*)d_in[7];
  const float* i_anw  = (const float*)d_in[8];
  const float* t_aw   = (const float*)d_in[9];
  const float* t_ab   = (const float*)d_in[10];
  const float* t_anw  = (const float*)d_in[11];
  const float* t_qkvw = (const float*)d_in[12];
  const float* i_qkvw = (const float*)d_in[13];
  const float* t_outw = (const float*)d_in[14];
  const float* i_outw = (const float*)d_in[15];
  const float* modw   = (const float*)d_in[16];
  const float* modb   = (const float*)d_in[17];
  const float* i_n2w  = (const float*)d_in[18];
  const float* t_n2w  = (const float*)d_in[19];
  const float* i_f1w  = (const float*)d_in[20];
  const float* i_f1b  = (const float*)d_in[21];
  const float* i_f2w  = (const float*)d_in[22];
  const float* i_f2b  = (const float*)d_in[23];
  const float* t_f1w  = (const float*)d_in[24];
  const float* t_f1b  = (const float*)d_in[25];
  const float* t_f2w  = (const float*)d_in[26];
  const float* t_f2b  = (const float*)d_in[27];
  float* ws = (float*)d_ws;
  float* out = (float*)d_out;

  hipLaunchKernelGGL(k_adaln, dim3(48), dim3(256), 0, stream, vec, t_aw, t_ab, i_aw, i_ab, ws);
  hipLaunchKernelGGL(k_mod, dim3(64), dim3(256), 0, stream, sspat, modw, modb, stemp, ws);
  hipLaunchKernelGGL((k_rmsmod<true>), dim3(B_ * T_), dim3(256), 0, stream,
                     txt, img, (const float*)nullptr, t_anw, i_anw, 0, 512, ws, ws + O_XN);
  hipLaunchKernelGGL(k_qkv, dim3(320 * 6), dim3(256), 0, stream, ws, ws, t_qkvw, i_qkvw);
  hipLaunchKernelGGL(k_ropemod, dim3(4096), dim3(256), 0, stream, ws, rope);
  hipLaunchKernelGGL(k_attn, dim3(640), dim3(256), 0, stream, ws, ws);
  hipLaunchKernelGGL(k_proj, dim3(640), dim3(256), 0, stream, ws, ws, txt, img, t_outw, i_outw);
  hipLaunchKernelGGL((k_rmsmod<false>), dim3(B_ * T_), dim3(256), 0, stream,
                     (const float*)nullptr, (const float*)nullptr, ws + O_X2, t_n2w, i_n2w,
                     1536, 2048, ws, ws + O_XIN2);
  hipLaunchKernelGGL(k_fc1, dim3(320 * 8), dim3(256), 0, stream, ws, ws, t_f1w, t_f1b, i_f1w, i_f1b);
  hipLaunchKernelGGL(k_fc2, dim3(320 * 2), dim3(256), 0, stream, ws, out, t_f2w, t_f2b, i_f2w, i_f2b);
}

// Round 3
// 1279.047 us; speedup vs baseline: 1.5039x; 1.5039x over previous
//
#include <hip/hip_runtime.h>
#include <math.h>

// Problem constants (fixed shapes from setup_inputs)
constexpr int B_  = 2;
constexpr int L_  = 512;    // txt tokens
constexpr int N_  = 2048;   // img tokens (H=64, W=32)
constexpr int T_  = 2560;   // L_+N_
constexpr int D_  = 512;
constexpr int NH_ = 4;
constexpr int HD_ = 128;
constexpr int FF_ = 2048;
constexpr int SIXD = 3072;
#define SCALE_ 0.08838834764831843f

// Workspace layout (floats).
constexpr size_t QSZ    = (size_t)B_ * NH_ * T_ * HD_;      // 2,621,440 (== B*T*D)
constexpr size_t O_ETXT = 0;
constexpr size_t O_EIMG = O_ETXT + (size_t)B_ * SIXD;       // 6144
constexpr size_t O_MOD  = O_EIMG + (size_t)B_ * SIXD;       // 12288
constexpr size_t O_EFF  = O_MOD + (size_t)B_ * NH_ * N_;    // 28672
constexpr size_t O_XN   = O_EFF + 16;                        // 28688
constexpr size_t O_Q    = O_XN + QSZ;
constexpr size_t O_K    = O_Q + QSZ;
constexpr size_t O_V    = O_K + QSZ;
constexpr size_t O_ATTN = O_V + QSZ;
constexpr size_t O_X2   = O_ATTN + QSZ;
constexpr size_t O_XIN2 = O_X2 + QSZ;
constexpr size_t O_H    = O_Q;   // reuse Q..ATTN region for MLP hidden

// ---------------- adaLN: e = silu(vec) @ W.T + b  (both streams) ----------------
__global__ __launch_bounds__(256) void k_adaln(const float* __restrict__ vec,
                                               const float* __restrict__ wt, const float* __restrict__ bt,
                                               const float* __restrict__ wi, const float* __restrict__ bi,
                                               float* __restrict__ ws) {
  int blk = blockIdx.x;
  int s = blk / (B_ * 12);
  int rem = blk % (B_ * 12);
  int b = rem / 12;
  int o = (rem % 12) * 256 + threadIdx.x;
  __shared__ float sv[D_];
  for (int i = threadIdx.x; i < D_; i += 256) {
    float x = vec[b * D_ + i];
    sv[i] = x / (1.0f + __expf(-x));
  }
  __syncthreads();
  const float* w = (s == 0) ? wt : wi;
  const float* bb = (s == 0) ? bt : bi;
  const float4* wrow = (const float4*)(w + (size_t)o * D_);
  float acc = 0.f;
  for (int d4 = 0; d4 < D_ / 4; ++d4) {
    float4 wv = wrow[d4];
    int d = d4 * 4;
    acc += wv.x * sv[d] + wv.y * sv[d + 1] + wv.z * sv[d + 2] + wv.w * sv[d + 3];
  }
  acc += bb[o];
  float* e = ws + ((s == 0) ? O_ETXT : O_EIMG);
  e[b * SIXD + o] = acc;
}

// ---------------- mod (bilinear upsample + affine + clip + exp) and eff ----------------
__global__ __launch_bounds__(256) void k_mod(const float* __restrict__ sspat,
                                             const float* __restrict__ mw, const float* __restrict__ mb,
                                             const float* __restrict__ stemp,
                                             float* __restrict__ ws) {
  int idx = blockIdx.x * 256 + threadIdx.x;  // B*NH*N = 16384
  if (idx < B_) {
    float s = 0.f;
    for (int h = 0; h < NH_; ++h) s += stemp[idx * NH_ + h];
    float t = fmaxf(s * 0.25f, 0.1f);
    ws[O_EFF + idx] = SCALE_ / t;
  }
  int b = idx / (NH_ * N_);
  int h = (idx / N_) % NH_;
  int n = idx % N_;
  int y = n >> 5;      // W=32
  int x = n & 31;
  float fy = (y + 0.5f) * 0.125f - 0.5f;
  float fx = (x + 0.5f) * 0.25f  - 0.5f;
  float y0f = floorf(fy), x0f = floorf(fx);
  float wy = fy - y0f, wx = fx - x0f;
  int y0 = (int)y0f, x0 = (int)x0f;
  int iy0 = y0 < 0 ? 0 : y0, iy1 = (y0 + 1) > 7 ? 7 : (y0 + 1);
  int ix0 = x0 < 0 ? 0 : x0, ix1 = (x0 + 1) > 7 ? 7 : (x0 + 1);
  const float* S = sspat + b * 64;
  float v00 = S[iy0*8+ix0], v01 = S[iy0*8+ix1];
  float v10 = S[iy1*8+ix0], v11 = S[iy1*8+ix1];
  float up = (1.f-wy)*((1.f-wx)*v00 + wx*v01) + wy*((1.f-wx)*v10 + wx*v11);
  float m = up * mw[h] + mb[h];
  m = fminf(fmaxf(m, -2.f), 2.f);
  ws[O_MOD + idx] = __expf(m);
}

// ---------------- rms + adaLN modulate: out = rms(x,w)*(1+sc)+sh ----------------
template<bool FROM_INPUT>
__global__ __launch_bounds__(256) void k_rmsmod(const float* __restrict__ txt, const float* __restrict__ img,
                                                const float* __restrict__ src_ws,
                                                const float* __restrict__ nw_txt, const float* __restrict__ nw_img,
                                                int sh_off, int sc_off,
                                                const float* __restrict__ e_ws,
                                                float* __restrict__ out) {
  int row = blockIdx.x;         // B*T rows
  int b = row / T_;
  int t = row % T_;
  bool is_txt = t < L_;
  int i0 = threadIdx.x * 2;
  float x0, x1;
  if (FROM_INPUT) {
    const float* src = is_txt ? (txt + ((size_t)b * L_ + t) * D_)
                              : (img + ((size_t)b * N_ + (t - L_)) * D_);
    x0 = src[i0]; x1 = src[i0 + 1];
  } else {
    const float* src = src_ws + (size_t)row * D_;
    x0 = src[i0]; x1 = src[i0 + 1];
  }
  float ss = x0 * x0 + x1 * x1;
  for (int off = 32; off; off >>= 1) ss += __shfl_down(ss, off, 64);
  __shared__ float red[4];
  if ((threadIdx.x & 63) == 0) red[threadIdx.x >> 6] = ss;
  __syncthreads();
  float tot = red[0] + red[1] + red[2] + red[3];
  float r = rsqrtf(tot * (1.0f / D_) + 1e-6f);
  const float* e = e_ws + (is_txt ? O_ETXT : O_EIMG) + (size_t)b * SIXD;
  const float* nw = is_txt ? nw_txt : nw_img;
  float* o = out + (size_t)row * D_;
  o[i0]     = x0 * r * nw[i0]     * (1.f + e[sc_off + i0])     + e[sh_off + i0];
  o[i0 + 1] = x1 * r * nw[i0 + 1] * (1.f + e[sc_off + i0 + 1]) + e[sh_off + i0 + 1];
}

// ---------------- shared GEMM core: 16 rows (LDS, broadcast) x 1 col/thread ----------------
__device__ __forceinline__ void gemm16(const float* xs, const float4* wrow, float* acc, int n8) {
  const float4* xs4 = (const float4*)xs;
  for (int d8 = 0; d8 < n8; ++d8) {
    float4 wa = wrow[d8 * 2];
    float4 wb = wrow[d8 * 2 + 1];
    #pragma unroll
    for (int r = 0; r < 16; ++r) {
      float4 a = xs4[r * 128 + d8 * 2];
      float4 c = xs4[r * 128 + d8 * 2 + 1];
      acc[r] += wa.x*a.x + wa.y*a.y + wa.z*a.z + wa.w*a.w
              + wb.x*c.x + wb.y*c.y + wb.z*c.z + wb.w*c.w;
    }
  }
}

// ---------------- QKV projection ----------------
__global__ __launch_bounds__(256) void k_qkv(const float* __restrict__ ws_ro, float* __restrict__ wsw,
                                             const float* __restrict__ wq_txt, const float* __restrict__ wq_img) {
  int rb = blockIdx.x / 6, jc = blockIdx.x % 6;
  int row0 = rb * 16;
  int b = row0 / T_, t0 = row0 % T_;
  bool is_txt = t0 < L_;
  __shared__ __align__(16) float xs[16 * D_];
  const float4* src4 = (const float4*)(ws_ro + O_XN + (size_t)row0 * D_);
  float4* xs4w = (float4*)xs;
  for (int i = threadIdx.x; i < 16 * D_ / 4; i += 256) xs4w[i] = src4[i];
  __syncthreads();
  int j = jc * 256 + threadIdx.x;  // 0..1535
  const float* w = is_txt ? wq_txt : wq_img;
  float acc[16];
  #pragma unroll
  for (int r = 0; r < 16; ++r) acc[r] = 0.f;
  gemm16(xs, (const float4*)(w + (size_t)j * D_), acc, D_ / 8);
  int which = j >> 9;
  int h = (j & 511) >> 7;
  int dd = j & 127;
  float* dst = wsw + (which == 0 ? O_Q : which == 1 ? O_K : O_V)
             + (((size_t)b * NH_ + h) * T_ + t0) * HD_ + dd;
  #pragma unroll
  for (int r = 0; r < 16; ++r) dst[(size_t)r * HD_] = acc[r];
}

// ---------------- RoPE + mod on img Q,K (in place) ----------------
__global__ __launch_bounds__(256) void k_ropemod(float* __restrict__ wsw, const float* __restrict__ rope) {
  int idx = blockIdx.x * 256 + threadIdx.x;  // B*NH*N*64 = 1,048,576
  int i = idx & 63;
  int p = idx >> 6;
  int n = p & (N_ - 1);
  int bh = p >> 11;            // b*NH+h
  float c = rope[(size_t)n * HD_ + 2 * i];
  float s = rope[(size_t)n * HD_ + 2 * i + 1];
  float m = wsw[O_MOD + (size_t)bh * N_ + n];
  size_t base = ((size_t)bh * T_ + (L_ + n)) * HD_ + 2 * i;
  float* Q = wsw + O_Q;
  float* K = wsw + O_K;
  float q0 = Q[base], q1 = Q[base + 1];
  Q[base]     = (q0 * c - q1 * s) * m;
  Q[base + 1] = (q1 * c + q0 * s) * m;
  float k0 = K[base], k1 = K[base + 1];
  K[base]     = (k0 * c - k1 * s) * m;
  K[base + 1] = (k1 * c + k0 * s) * m;
}

// ---------------- MFMA flash attention ----------------
// Q-tile 32 rows (2 waves x 16), K-tile 32 keys, hi/lo bf16 split for QK^T,
// hi-only for P and V. grid = B*NH*(T/32) = 640, 128 threads.
typedef short bf16x8 __attribute__((ext_vector_type(8)));
typedef float f32x4 __attribute__((ext_vector_type(4)));

__device__ __forceinline__ unsigned short f2bf_rne(float x) {
  unsigned u = __float_as_uint(x);
  u += 0x7fff + ((u >> 16) & 1);
  return (unsigned short)(u >> 16);
}

__device__ __forceinline__ void split_store4(float4 v, unsigned short* hi, unsigned short* lo) {
  ushort4 h, l;
  h.x = f2bf_rne(v.x); l.x = f2bf_rne(v.x - __uint_as_float((unsigned)h.x << 16));
  h.y = f2bf_rne(v.y); l.y = f2bf_rne(v.y - __uint_as_float((unsigned)h.y << 16));
  h.z = f2bf_rne(v.z); l.z = f2bf_rne(v.z - __uint_as_float((unsigned)h.z << 16));
  h.w = f2bf_rne(v.w); l.w = f2bf_rne(v.w - __uint_as_float((unsigned)h.w << 16));
  *(ushort4*)hi = h; *(ushort4*)lo = l;
}

__global__ __launch_bounds__(128) void k_attn_mfma(const float* __restrict__ ws_ro, float* __restrict__ wsw) {
  int qt = blockIdx.x % 80;
  int bh = blockIdx.x / 80;
  int b = bh >> 2, h = bh & 3;
  int q0 = qt * 32;
  float scale = (q0 < L_) ? SCALE_ : ws_ro[O_EFF + b];

  const float* Qg = ws_ro + O_Q + ((size_t)bh * T_ + q0) * HD_;
  const float* Kg = ws_ro + O_K + (size_t)bh * T_ * HD_;
  const float* Vg = ws_ro + O_V + (size_t)bh * T_ * HD_;

  // LDS: K hi/lo [32][136] (pad 8 -> 2-way bank aliasing, free), V^T [128][40], P [2][16][40]
  __shared__ __align__(16) unsigned short ks_hi[32 * 136];
  __shared__ __align__(16) unsigned short ks_lo[32 * 136];
  __shared__ __align__(16) unsigned short vt_hi[128 * 40];
  __shared__ __align__(16) unsigned short ps[2 * 16 * 40];

  int tid = threadIdx.x;
  int w = tid >> 6, lane = tid & 63;
  int quad = lane >> 4, lc = lane & 15;

  // ---- Q fragments direct from global (A-layout: m=lane&15, k=quad*8+j), scaled + hi/lo split ----
  bf16x8 qh[4], ql[4];
  {
    const float* qrowp = Qg + (size_t)(w * 16 + lc) * HD_ + quad * 8;
    #pragma unroll
    for (int k2 = 0; k2 < 4; ++k2) {
      float4 a = *(const float4*)(qrowp + k2 * 32);
      float4 c = *(const float4*)(qrowp + k2 * 32 + 4);
      float v[8] = {a.x, a.y, a.z, a.w, c.x, c.y, c.z, c.w};
      #pragma unroll
      for (int e = 0; e < 8; ++e) {
        float x = v[e] * scale;
        unsigned short hh = f2bf_rne(x);
        float hf = __uint_as_float((unsigned)hh << 16);
        unsigned short ll = f2bf_rne(x - hf);
        qh[k2][e] = (short)hh;
        ql[k2][e] = (short)ll;
      }
    }
  }

  f32x4 o[8];
  #pragma unroll
  for (int i = 0; i < 8; ++i) o[i] = f32x4{0.f, 0.f, 0.f, 0.f};
  float m_r[4] = {-1e30f, -1e30f, -1e30f, -1e30f};
  float l_r[4] = {0.f, 0.f, 0.f, 0.f};

  for (int kt = 0; kt < T_ / 32; ++kt) {
    // ---- stage K tile hi/lo (coalesced) ----
    {
      int row = tid >> 2, f4l = tid & 3;
      const float4* src = (const float4*)(Kg + (size_t)(kt * 32 + row) * HD_);
      #pragma unroll
      for (int i = 0; i < 8; ++i) {
        int f4i = i * 4 + f4l;
        float4 v = src[f4i];
        split_store4(v, &ks_hi[row * 136 + f4i * 4], &ks_lo[row * 136 + f4i * 4]);
      }
    }
    // ---- stage V transposed (key-pairs packed into u32 writes) ----
    {
      int kp = tid & 15, ch = tid >> 4;   // kp: key pair, ch: 16-d chunk
      const float* v0 = Vg + (size_t)(kt * 32 + 2 * kp) * HD_ + ch * 16;
      const float* v1 = v0 + HD_;
      #pragma unroll
      for (int i = 0; i < 4; ++i) {
        float4 x0 = ((const float4*)v0)[i];
        float4 x1 = ((const float4*)v1)[i];
        int d = ch * 16 + i * 4;
        *(unsigned*)&vt_hi[(d + 0) * 40 + 2 * kp] = (unsigned)f2bf_rne(x0.x) | ((unsigned)f2bf_rne(x1.x) << 16);
        *(unsigned*)&vt_hi[(d + 1) * 40 + 2 * kp] = (unsigned)f2bf_rne(x0.y) | ((unsigned)f2bf_rne(x1.y) << 16);
        *(unsigned*)&vt_hi[(d + 2) * 40 + 2 * kp] = (unsigned)f2bf_rne(x0.z) | ((unsigned)f2bf_rne(x1.z) << 16);
        *(unsigned*)&vt_hi[(d + 3) * 40 + 2 * kp] = (unsigned)f2bf_rne(x0.w) | ((unsigned)f2bf_rne(x1.w) << 16);
      }
    }
    __syncthreads();

    // ---- S = Q K^T (3-term hi/lo), two 16-key N-tiles ----
    f32x4 s0 = {0.f, 0.f, 0.f, 0.f}, s1 = {0.f, 0.f, 0.f, 0.f};
    #pragma unroll
    for (int k2 = 0; k2 < 4; ++k2) {
      int koff = k2 * 32 + quad * 8;
      bf16x8 kh0 = *(const bf16x8*)&ks_hi[lc * 136 + koff];
      bf16x8 kl0 = *(const bf16x8*)&ks_lo[lc * 136 + koff];
      bf16x8 kh1 = *(const bf16x8*)&ks_hi[(lc + 16) * 136 + koff];
      bf16x8 kl1 = *(const bf16x8*)&ks_lo[(lc + 16) * 136 + koff];
      s0 = __builtin_amdgcn_mfma_f32_16x16x32_bf16(ql[k2], kh0, s0, 0, 0, 0);
      s0 = __builtin_amdgcn_mfma_f32_16x16x32_bf16(qh[k2], kl0, s0, 0, 0, 0);
      s0 = __builtin_amdgcn_mfma_f32_16x16x32_bf16(qh[k2], kh0, s0, 0, 0, 0);
      s1 = __builtin_amdgcn_mfma_f32_16x16x32_bf16(ql[k2], kh1, s1, 0, 0, 0);
      s1 = __builtin_amdgcn_mfma_f32_16x16x32_bf16(qh[k2], kl1, s1, 0, 0, 0);
      s1 = __builtin_amdgcn_mfma_f32_16x16x32_bf16(qh[k2], kh1, s1, 0, 0, 0);
    }

    // ---- online softmax (rows live in 16-lane groups; reg r -> row quad*4+r) ----
    float alpha[4];
    #pragma unroll
    for (int r = 0; r < 4; ++r) {
      float rm = fmaxf(s0[r], s1[r]);
      rm = fmaxf(rm, __shfl_xor(rm, 1, 64));
      rm = fmaxf(rm, __shfl_xor(rm, 2, 64));
      rm = fmaxf(rm, __shfl_xor(rm, 4, 64));
      rm = fmaxf(rm, __shfl_xor(rm, 8, 64));
      float mn = fmaxf(m_r[r], rm);
      alpha[r] = __expf(m_r[r] - mn);
      m_r[r] = mn;
      float p0 = __expf(s0[r] - mn);
      float p1 = __expf(s1[r] - mn);
      float rs = p0 + p1;
      rs += __shfl_xor(rs, 1, 64);
      rs += __shfl_xor(rs, 2, 64);
      rs += __shfl_xor(rs, 4, 64);
      rs += __shfl_xor(rs, 8, 64);
      l_r[r] = l_r[r] * alpha[r] + rs;
      int prow = quad * 4 + r;
      ps[w * 640 + prow * 40 + lc]      = f2bf_rne(p0);
      ps[w * 640 + prow * 40 + lc + 16] = f2bf_rne(p1);
    }
    #pragma unroll
    for (int dt = 0; dt < 8; ++dt) {
      #pragma unroll
      for (int r = 0; r < 4; ++r) o[dt][r] *= alpha[r];
    }

    // ---- O += P V  (A from wave-private ps, B from vt) ----
    bf16x8 pa = *(const bf16x8*)&ps[w * 640 + lc * 40 + quad * 8];
    #pragma unroll
    for (int dt = 0; dt < 8; ++dt) {
      bf16x8 vb = *(const bf16x8*)&vt_hi[(dt * 16 + lc) * 40 + quad * 8];
      o[dt] = __builtin_amdgcn_mfma_f32_16x16x32_bf16(pa, vb, o[dt], 0, 0, 0);
    }
    __syncthreads();
  }

  // ---- normalize + store to ATTN [b][t][h*128+d] ----
  int trow0 = q0 + w * 16 + quad * 4;
  #pragma unroll
  for (int r = 0; r < 4; ++r) {
    float inv = 1.0f / l_r[r];
    size_t base = O_ATTN + ((size_t)b * T_ + (trow0 + r)) * D_ + h * HD_ + lc;
    #pragma unroll
    for (int dt = 0; dt < 8; ++dt)
      wsw[base + dt * 16] = o[dt][r] * inv;
  }
}

// ---------------- out projection + gate + residual ----------------
__global__ __launch_bounds__(256) void k_proj(const float* __restrict__ ws_ro, float* __restrict__ wsw,
                                              const float* __restrict__ txt, const float* __restrict__ img,
                                              const float* __restrict__ w_txt, const float* __restrict__ w_img) {
  int rb = blockIdx.x >> 1, jc = blockIdx.x & 1;
  int row0 = rb * 16;
  int b = row0 / T_, t0 = row0 % T_;
  bool is_txt = t0 < L_;
  __shared__ __align__(16) float xs[16 * D_];
  const float4* src4 = (const float4*)(ws_ro + O_ATTN + (size_t)row0 * D_);
  float4* xs4w = (float4*)xs;
  for (int i = threadIdx.x; i < 16 * D_ / 4; i += 256) xs4w[i] = src4[i];
  __syncthreads();
  int j = jc * 256 + threadIdx.x;
  const float* w = is_txt ? w_txt : w_img;
  float acc[16];
  #pragma unroll
  for (int r = 0; r < 16; ++r) acc[r] = 0.f;
  gemm16(xs, (const float4*)(w + (size_t)j * D_), acc, D_ / 8);
  const float* e = ws_ro + (is_txt ? O_ETXT : O_EIMG) + (size_t)b * SIXD;
  float g = e[1024 + j];
  float* x2 = wsw + O_X2;
  #pragma unroll
  for (int r = 0; r < 16; ++r) {
    int t = t0 + r;
    float xin = is_txt ? txt[((size_t)b * L_ + t) * D_ + j]
                       : img[((size_t)b * N_ + (t - L_)) * D_ + j];
    x2[(size_t)(row0 + r) * D_ + j] = xin + g * acc[r];
  }
}

// ---------------- fc1 + gelu(tanh) ----------------
__global__ __launch_bounds__(256) void k_fc1(const float* __restrict__ ws_ro, float* __restrict__ wsw,
                                             const float* __restrict__ wt, const float* __restrict__ bt,
                                             const float* __restrict__ wi, const float* __restrict__ bi) {
  int rb = blockIdx.x >> 3, jc = blockIdx.x & 7;
  int row0 = rb * 16;
  int t0 = row0 % T_;
  bool is_txt = t0 < L_;
  __shared__ __align__(16) float xs[16 * D_];
  const float4* src4 = (const float4*)(ws_ro + O_XIN2 + (size_t)row0 * D_);
  float4* xs4w = (float4*)xs;
  for (int i = threadIdx.x; i < 16 * D_ / 4; i += 256) xs4w[i] = src4[i];
  __syncthreads();
  int j = jc * 256 + threadIdx.x;  // 0..2047
  const float* w = is_txt ? wt : wi;
  const float* bb = is_txt ? bt : bi;
  float acc[16];
  #pragma unroll
  for (int r = 0; r < 16; ++r) acc[r] = 0.f;
  gemm16(xs, (const float4*)(w + (size_t)j * D_), acc, D_ / 8);
  float bias = bb[j];
  #pragma unroll
  for (int r = 0; r < 16; ++r) {
    float x = acc[r] + bias;
    float th = tanhf(0.7978845608028654f * (x + 0.044715f * x * x * x));
    wsw[O_H + (size_t)(row0 + r) * FF_ + j] = 0.5f * x * (1.f + th);
  }
}

// ---------------- fc2 + gate + residual -> f32 out ----------------
__global__ __launch_bounds__(256) void k_fc2(const float* __restrict__ ws_ro, float* __restrict__ out,
                                             const float* __restrict__ wt, const float* __restrict__ bt,
                                             const float* __restrict__ wi, const float* __restrict__ bi) {
  int rb = blockIdx.x >> 1, jc = blockIdx.x & 1;
  int row0 = rb * 16;
  int b = row0 / T_, t0 = row0 % T_;
  bool is_txt = t0 < L_;
  __shared__ __align__(16) float xs[16 * D_];
  float4* xs4w = (float4*)xs;
  int j = jc * 256 + threadIdx.x;  // 0..511
  const float* w = is_txt ? wt : wi;
  const float* bb = is_txt ? bt : bi;
  float acc[16];
  #pragma unroll
  for (int r = 0; r < 16; ++r) acc[r] = 0.f;
  for (int kc = 0; kc < 4; ++kc) {
    __syncthreads();
    const float* hsrc = ws_ro + O_H + (size_t)row0 * FF_ + kc * 512;
    for (int i = threadIdx.x; i < 16 * 512 / 4; i += 256) {
      int r = i >> 7, d4 = i & 127;
      xs4w[i] = ((const float4*)(hsrc + (size_t)r * FF_))[d4];
    }
    __syncthreads();
    gemm16(xs, (const float4*)(w + (size_t)j * FF_ + kc * 512), acc, 64);
  }
  float bias = bb[j];
  const float* e = ws_ro + (is_txt ? O_ETXT : O_EIMG) + (size_t)b * SIXD;
  float g = e[2560 + j];
  #pragma unroll
  for (int r = 0; r < 16; ++r) {
    int t = t0 + r;
    float res = ws_ro[O_X2 + (size_t)(row0 + r) * D_ + j];
    float val = res + g * (acc[r] + bias);
    size_t o = is_txt ? ((size_t)b * L_ + t) * D_ + j
                      : (size_t)B_ * L_ * D_ + ((size_t)b * N_ + (t - L_)) * D_ + j;
    out[o] = val;
  }
}

extern "C" void kernel_launch(void* const* d_in, const int* in_sizes, int n_in,
                              void* d_out, int out_size, void* d_ws, size_t ws_size,
                              hipStream_t stream) {
  (void)in_sizes; (void)n_in; (void)out_size; (void)ws_size;
  const float* txt    = (const float*)d_in[0];
  const float* img    = (const float*)d_in[1];
  const float* vec    = (const float*)d_in[2];
  const float* rope   = (const float*)d_in[3];
  const float* stemp  = (const float*)d_in[4];
  const float* sspat  = (const float*)d_in[5];
  const float* i_aw   = (const float*)d_in[6];
  const float* i_ab   = (const float*)d_in[7];
  const float* i_anw  = (const float*)d_in[8];
  const float* t_aw   = (const float*)d_in[9];
  const float* t_ab   = (const float*)d_in[10];
  const float* t_anw  = (const float*)d_in[11];
  const float* t_qkvw = (const float*)d_in[12];
  const float* i_qkvw = (const float*)d_in[13];
  const float* t_outw = (const float*)d_in[14];
  const float* i_outw = (const float*)d_in[15];
  const float* modw   = (const float*)d_in[16];
  const float* modb   = (const float*)d_in[17];
  const float* i_n2w  = (const float*)d_in[18];
  const float* t_n2w  = (const float*)d_in[19];
  const float* i_f1w  = (const float*)d_in[20];
  const float* i_f1b  = (const float*)d_in[21];
  const float* i_f2w  = (const float*)d_in[22];
  const float* i_f2b  = (const float*)d_in[23];
  const float* t_f1w  = (const float*)d_in[24];
  const float* t_f1b  = (const float*)d_in[25];
  const float* t_f2w  = (const float*)d_in[26];
  const float* t_f2b  = (const float*)d_in[27];
  float* ws = (float*)d_ws;
  float* out = (float*)d_out;

  hipLaunchKernelGGL(k_adaln, dim3(48), dim3(256), 0, stream, vec, t_aw, t_ab, i_aw, i_ab, ws);
  hipLaunchKernelGGL(k_mod, dim3(64), dim3(256), 0, stream, sspat, modw, modb, stemp, ws);
  hipLaunchKernelGGL((k_rmsmod<true>), dim3(B_ * T_), dim3(256), 0, stream,
                     txt, img, (const float*)nullptr, t_anw, i_anw, 0, 512, ws, ws + O_XN);
  hipLaunchKernelGGL(k_qkv, dim3(320 * 6), dim3(256), 0, stream, ws, ws, t_qkvw, i_qkvw);
  hipLaunchKernelGGL(k_ropemod, dim3(4096), dim3(256), 0, stream, ws, rope);
  hipLaunchKernelGGL(k_attn_mfma, dim3(640), dim3(128), 0, stream, ws, ws);
  hipLaunchKernelGGL(k_proj, dim3(640), dim3(256), 0, stream, ws, ws, txt, img, t_outw, i_outw);
  hipLaunchKernelGGL((k_rmsmod<false>), dim3(B_ * T_), dim3(256), 0, stream,
                     (const float*)nullptr, (const float*)nullptr, ws + O_X2, t_n2w, i_n2w,
                     1536, 2048, ws, ws + O_XIN2);
  hipLaunchKernelGGL(k_fc1, dim3(320 * 8), dim3(256), 0, stream, ws, ws, t_f1w, t_f1b, i_f1w, i_f1b);
  hipLaunchKernelGGL(k_fc2, dim3(320 * 2), dim3(256), 0, stream, ws, out, t_f2w, t_f2b, i_f2w, i_f2b);
}

// Round 4
// 663.852 us; speedup vs baseline: 2.8977x; 1.9267x over previous
//
#include <hip/hip_runtime.h>
#include <math.h>

// Problem constants (fixed shapes from setup_inputs)
constexpr int B_  = 2;
constexpr int L_  = 512;    // txt tokens
constexpr int N_  = 2048;   // img tokens (H=64, W=32)
constexpr int T_  = 2560;   // L_+N_
constexpr int D_  = 512;
constexpr int NH_ = 4;
constexpr int HD_ = 128;
constexpr int FF_ = 2048;
constexpr int SIXD = 3072;
constexpr int MROWS = B_ * T_;   // 5120
#define SCALE_ 0.08838834764831843f

// Workspace layout (floats). Packed hi/lo activations reuse the same regions
// (u32 per element = same size as f32).
constexpr size_t QSZ    = (size_t)B_ * NH_ * T_ * HD_;      // 2,621,440 (== B*T*D)
constexpr size_t O_ETXT = 0;
constexpr size_t O_EIMG = O_ETXT + (size_t)B_ * SIXD;       // 6144
constexpr size_t O_MOD  = O_EIMG + (size_t)B_ * SIXD;       // 12288
constexpr size_t O_EFF  = O_MOD + (size_t)B_ * NH_ * N_;    // 28672
constexpr size_t O_XN   = O_EFF + 16;                        // packed u32 [5120][512]
constexpr size_t O_Q    = O_XN + QSZ;                        // f32
constexpr size_t O_K    = O_Q + QSZ;                         // f32
constexpr size_t O_V    = O_K + QSZ;                         // f32
constexpr size_t O_ATTN = O_V + QSZ;                         // packed u32 [5120][512]
constexpr size_t O_X2   = O_ATTN + QSZ;                      // f32
constexpr size_t O_XIN2 = O_X2 + QSZ;                        // packed u32 [5120][512]
constexpr size_t O_H    = O_Q;   // packed u32 [5120][2048] over Q..ATTN span (4*QSZ)

typedef short bf16x8 __attribute__((ext_vector_type(8)));
typedef float f32x4 __attribute__((ext_vector_type(4)));

__device__ __forceinline__ unsigned short f2bf_rne(float x) {
  unsigned u = __float_as_uint(x);
  u += 0x7fff + ((u >> 16) & 1);
  return (unsigned short)(u >> 16);
}
// pack f32 -> (hi bf16 << 16) | lo bf16, hi+lo ~ 17-bit-accurate representation
__device__ __forceinline__ unsigned packhl(float x) {
  unsigned short h = f2bf_rne(x);
  float lof = x - __uint_as_float((unsigned)h << 16);
  unsigned short l = f2bf_rne(lof);
  return ((unsigned)h << 16) | (unsigned)l;
}

// ---------------- adaLN: e = silu(vec) @ W.T + b  (both streams) ----------------
__global__ __launch_bounds__(256) void k_adaln(const float* __restrict__ vec,
                                               const float* __restrict__ wt, const float* __restrict__ bt,
                                               const float* __restrict__ wi, const float* __restrict__ bi,
                                               float* __restrict__ ws) {
  int blk = blockIdx.x;
  int s = blk / (B_ * 12);
  int rem = blk % (B_ * 12);
  int b = rem / 12;
  int o = (rem % 12) * 256 + threadIdx.x;
  __shared__ float sv[D_];
  for (int i = threadIdx.x; i < D_; i += 256) {
    float x = vec[b * D_ + i];
    sv[i] = x / (1.0f + __expf(-x));
  }
  __syncthreads();
  const float* w = (s == 0) ? wt : wi;
  const float* bb = (s == 0) ? bt : bi;
  const float4* wrow = (const float4*)(w + (size_t)o * D_);
  float acc = 0.f;
  for (int d4 = 0; d4 < D_ / 4; ++d4) {
    float4 wv = wrow[d4];
    int d = d4 * 4;
    acc += wv.x * sv[d] + wv.y * sv[d + 1] + wv.z * sv[d + 2] + wv.w * sv[d + 3];
  }
  acc += bb[o];
  float* e = ws + ((s == 0) ? O_ETXT : O_EIMG);
  e[b * SIXD + o] = acc;
}

// ---------------- mod (bilinear upsample + affine + clip + exp) and eff ----------------
__global__ __launch_bounds__(256) void k_mod(const float* __restrict__ sspat,
                                             const float* __restrict__ mw, const float* __restrict__ mb,
                                             const float* __restrict__ stemp,
                                             float* __restrict__ ws) {
  int idx = blockIdx.x * 256 + threadIdx.x;  // B*NH*N = 16384
  if (idx < B_) {
    float s = 0.f;
    for (int h = 0; h < NH_; ++h) s += stemp[idx * NH_ + h];
    float t = fmaxf(s * 0.25f, 0.1f);
    ws[O_EFF + idx] = SCALE_ / t;
  }
  int b = idx / (NH_ * N_);
  int h = (idx / N_) % NH_;
  int n = idx % N_;
  int y = n >> 5;      // W=32
  int x = n & 31;
  float fy = (y + 0.5f) * 0.125f - 0.5f;
  float fx = (x + 0.5f) * 0.25f  - 0.5f;
  float y0f = floorf(fy), x0f = floorf(fx);
  float wy = fy - y0f, wx = fx - x0f;
  int y0 = (int)y0f, x0 = (int)x0f;
  int iy0 = y0 < 0 ? 0 : y0, iy1 = (y0 + 1) > 7 ? 7 : (y0 + 1);
  int ix0 = x0 < 0 ? 0 : x0, ix1 = (x0 + 1) > 7 ? 7 : (x0 + 1);
  const float* S = sspat + b * 64;
  float v00 = S[iy0*8+ix0], v01 = S[iy0*8+ix1];
  float v10 = S[iy1*8+ix0], v11 = S[iy1*8+ix1];
  float up = (1.f-wy)*((1.f-wx)*v00 + wx*v01) + wy*((1.f-wx)*v10 + wx*v11);
  float m = up * mw[h] + mb[h];
  m = fminf(fmaxf(m, -2.f), 2.f);
  ws[O_MOD + idx] = __expf(m);
}

// ---------------- rms + adaLN modulate -> packed hi/lo u32 ----------------
template<bool FROM_INPUT>
__global__ __launch_bounds__(256) void k_rmsmod(const float* __restrict__ txt, const float* __restrict__ img,
                                                const float* __restrict__ src_ws,
                                                const float* __restrict__ nw_txt, const float* __restrict__ nw_img,
                                                int sh_off, int sc_off,
                                                const float* __restrict__ e_ws,
                                                unsigned* __restrict__ outp) {
  int row = blockIdx.x;         // B*T rows
  int b = row / T_;
  int t = row % T_;
  bool is_txt = t < L_;
  int i0 = threadIdx.x * 2;
  float x0, x1;
  if (FROM_INPUT) {
    const float* src = is_txt ? (txt + ((size_t)b * L_ + t) * D_)
                              : (img + ((size_t)b * N_ + (t - L_)) * D_);
    x0 = src[i0]; x1 = src[i0 + 1];
  } else {
    const float* src = src_ws + (size_t)row * D_;
    x0 = src[i0]; x1 = src[i0 + 1];
  }
  float ss = x0 * x0 + x1 * x1;
  for (int off = 32; off; off >>= 1) ss += __shfl_down(ss, off, 64);
  __shared__ float red[4];
  if ((threadIdx.x & 63) == 0) red[threadIdx.x >> 6] = ss;
  __syncthreads();
  float tot = red[0] + red[1] + red[2] + red[3];
  float r = rsqrtf(tot * (1.0f / D_) + 1e-6f);
  const float* e = e_ws + (is_txt ? O_ETXT : O_EIMG) + (size_t)b * SIXD;
  const float* nw = is_txt ? nw_txt : nw_img;
  float y0 = x0 * r * nw[i0]     * (1.f + e[sc_off + i0])     + e[sh_off + i0];
  float y1 = x1 * r * nw[i0 + 1] * (1.f + e[sc_off + i0 + 1]) + e[sh_off + i0 + 1];
  uint2 pk; pk.x = packhl(y0); pk.y = packhl(y1);
  *(uint2*)&outp[(size_t)row * D_ + i0] = pk;
}

// ---------------- templated MFMA GEMM: C[128 x NTILE] = A . W^T ----------------
// A: packed hi/lo u32 [M][K]; W: f32 [N][K] (converted to bf16 in staging).
// NTERMS=2: (Ah+Al).Wh ; NTERMS=3: + Ah.Wl (for QKV accuracy).
// EPI: 0=QKV scatter, 1=proj gate+residual->X2, 2=fc1 bias+gelu->packed H, 3=fc2 bias+gate+residual->out
template<int NTILE, int NTERMS, int KDIM, int NPR, int EPI>
__global__ __launch_bounds__(256) void k_gemm(
    const unsigned* __restrict__ Ap,
    const float* __restrict__ Wt, const float* __restrict__ Wi,
    const float* __restrict__ biast, const float* __restrict__ biasi,
    const float* __restrict__ ws_ro, float* __restrict__ wsw,
    const float* __restrict__ txt, const float* __restrict__ img,
    unsigned* __restrict__ Hp, float* __restrict__ outf) {
  int mt = blockIdx.x / NPR, nt = blockIdx.x % NPR;
  int row0 = mt * 128;
  int col0 = nt * NTILE;
  int b = row0 / T_;
  int t0 = row0 % T_;
  bool is_txt = t0 < L_;
  const float* W = is_txt ? Wt : Wi;

  __shared__ __align__(16) unsigned short ash[128 * 40];
  __shared__ __align__(16) unsigned short asl[128 * 40];
  __shared__ __align__(16) unsigned short bsh[NTILE * 40];
  __shared__ __align__(16) unsigned short bsl[(NTERMS == 3) ? NTILE * 40 : 8];

  int tid = threadIdx.x;
  int w = tid >> 6, lane = tid & 63, quad = lane >> 4, lc = lane & 15;
  int rh = w >> 1, ch = w & 1;
  constexpr int NFR = NTILE / 32;   // n-frags per wave

  f32x4 acc[4][NFR];
  #pragma unroll
  for (int m = 0; m < 4; ++m)
    #pragma unroll
    for (int n = 0; n < NFR; ++n) acc[m][n] = f32x4{0.f, 0.f, 0.f, 0.f};

  for (int kt = 0; kt < KDIM / 32; ++kt) {
    // ---- stage A (packed hi/lo): 128 rows x 32 k ----
    {
      int r = tid >> 1, koff = (tid & 1) * 16;
      const unsigned* src = Ap + (size_t)(row0 + r) * KDIM + kt * 32 + koff;
      unsigned pw[16];
      *(uint4*)&pw[0]  = ((const uint4*)src)[0];
      *(uint4*)&pw[4]  = ((const uint4*)src)[1];
      *(uint4*)&pw[8]  = ((const uint4*)src)[2];
      *(uint4*)&pw[12] = ((const uint4*)src)[3];
      unsigned hw[8], lw[8];
      #pragma unroll
      for (int e2 = 0; e2 < 8; ++e2) {
        unsigned x = pw[2 * e2], y = pw[2 * e2 + 1];
        hw[e2] = (x >> 16) | (y & 0xffff0000u);
        lw[e2] = (x & 0xffffu) | (y << 16);
      }
      *(uint4*)&ash[r * 40 + koff]     = *(uint4*)&hw[0];
      *(uint4*)&ash[r * 40 + koff + 8] = *(uint4*)&hw[4];
      *(uint4*)&asl[r * 40 + koff]     = *(uint4*)&lw[0];
      *(uint4*)&asl[r * 40 + koff + 8] = *(uint4*)&lw[4];
    }
    // ---- stage W (f32 -> bf16 hi [+lo]): NTILE rows x 32 k ----
    {
      constexpr int NW = NTILE * 8 / 256;
      #pragma unroll
      for (int wc = 0; wc < NW; ++wc) {
        int idx = wc * 256 + tid;
        int rw = idx >> 3, c4 = idx & 7;
        float4 v = *(const float4*)(W + (size_t)(col0 + rw) * KDIM + kt * 32 + c4 * 4);
        ushort4 hh;
        hh.x = f2bf_rne(v.x); hh.y = f2bf_rne(v.y); hh.z = f2bf_rne(v.z); hh.w = f2bf_rne(v.w);
        *(ushort4*)&bsh[rw * 40 + c4 * 4] = hh;
        if (NTERMS == 3) {
          ushort4 ll;
          ll.x = f2bf_rne(v.x - __uint_as_float((unsigned)hh.x << 16));
          ll.y = f2bf_rne(v.y - __uint_as_float((unsigned)hh.y << 16));
          ll.z = f2bf_rne(v.z - __uint_as_float((unsigned)hh.z << 16));
          ll.w = f2bf_rne(v.w - __uint_as_float((unsigned)hh.w << 16));
          *(ushort4*)&bsl[rw * 40 + c4 * 4] = ll;
        }
      }
    }
    __syncthreads();

    bf16x8 afh[4], afl[4];
    #pragma unroll
    for (int m = 0; m < 4; ++m) {
      int ar = rh * 64 + m * 16 + lc;
      afh[m] = *(const bf16x8*)&ash[ar * 40 + quad * 8];
      afl[m] = *(const bf16x8*)&asl[ar * 40 + quad * 8];
    }
    #pragma unroll
    for (int n = 0; n < NFR; ++n) {
      int br = ch * (NTILE / 2) + n * 16 + lc;
      bf16x8 bh = *(const bf16x8*)&bsh[br * 40 + quad * 8];
      if (NTERMS == 3) {
        bf16x8 bl = *(const bf16x8*)&bsl[br * 40 + quad * 8];
        #pragma unroll
        for (int m = 0; m < 4; ++m) {
          acc[m][n] = __builtin_amdgcn_mfma_f32_16x16x32_bf16(afl[m], bh, acc[m][n], 0, 0, 0);
          acc[m][n] = __builtin_amdgcn_mfma_f32_16x16x32_bf16(afh[m], bl, acc[m][n], 0, 0, 0);
          acc[m][n] = __builtin_amdgcn_mfma_f32_16x16x32_bf16(afh[m], bh, acc[m][n], 0, 0, 0);
        }
      } else {
        #pragma unroll
        for (int m = 0; m < 4; ++m) {
          acc[m][n] = __builtin_amdgcn_mfma_f32_16x16x32_bf16(afl[m], bh, acc[m][n], 0, 0, 0);
          acc[m][n] = __builtin_amdgcn_mfma_f32_16x16x32_bf16(afh[m], bh, acc[m][n], 0, 0, 0);
        }
      }
    }
    __syncthreads();
  }

  // ---- epilogue ----
  const float* e = ws_ro + (is_txt ? O_ETXT : O_EIMG) + (size_t)b * SIXD;
  const float* bias = is_txt ? biast : biasi;
  #pragma unroll
  for (int m = 0; m < 4; ++m) {
    #pragma unroll
    for (int n = 0; n < NFR; ++n) {
      #pragma unroll
      for (int r = 0; r < 4; ++r) {
        int rg = row0 + rh * 64 + m * 16 + quad * 4 + r;
        int cg = col0 + ch * (NTILE / 2) + n * 16 + lc;
        float val = acc[m][n][r];
        int tt = rg % T_;
        if (EPI == 0) {
          int which = cg >> 9, h = (cg >> 7) & 3, dd = cg & 127;
          float* dst = wsw + (which == 0 ? O_Q : which == 1 ? O_K : O_V)
                     + (((size_t)b * NH_ + h) * T_ + tt) * HD_ + dd;
          *dst = val;
        } else if (EPI == 1) {
          float g = e[1024 + cg];
          float res = is_txt ? txt[((size_t)b * L_ + tt) * D_ + cg]
                             : img[((size_t)b * N_ + (tt - L_)) * D_ + cg];
          wsw[O_X2 + (size_t)rg * D_ + cg] = res + g * val;
        } else if (EPI == 2) {
          float x = val + bias[cg];
          float z = 0.7978845608028654f * (x + 0.044715f * x * x * x);
          z = fminf(fmaxf(z, -40.f), 40.f);
          float u = __expf(-2.f * z);
          float th = (1.f - u) / (1.f + u);
          Hp[(size_t)rg * FF_ + cg] = packhl(0.5f * x * (1.f + th));
        } else {
          float g = e[2560 + cg];
          float v2 = ws_ro[O_X2 + (size_t)rg * D_ + cg] + g * (val + bias[cg]);
          size_t oi = is_txt ? ((size_t)b * L_ + tt) * D_ + cg
                             : (size_t)B_ * L_ * D_ + ((size_t)b * N_ + (tt - L_)) * D_ + cg;
          outf[oi] = v2;
        }
      }
    }
  }
}

// ---------------- RoPE + mod on img Q,K (in place, f32) ----------------
__global__ __launch_bounds__(256) void k_ropemod(float* __restrict__ wsw, const float* __restrict__ rope) {
  int idx = blockIdx.x * 256 + threadIdx.x;  // B*NH*N*64 = 1,048,576
  int i = idx & 63;
  int p = idx >> 6;
  int n = p & (N_ - 1);
  int bh = p >> 11;            // b*NH+h
  float c = rope[(size_t)n * HD_ + 2 * i];
  float s = rope[(size_t)n * HD_ + 2 * i + 1];
  float m = wsw[O_MOD + (size_t)bh * N_ + n];
  size_t base = ((size_t)bh * T_ + (L_ + n)) * HD_ + 2 * i;
  float* Q = wsw + O_Q;
  float* K = wsw + O_K;
  float q0 = Q[base], q1 = Q[base + 1];
  Q[base]     = (q0 * c - q1 * s) * m;
  Q[base + 1] = (q1 * c + q0 * s) * m;
  float k0 = K[base], k1 = K[base + 1];
  K[base]     = (k0 * c - k1 * s) * m;
  K[base + 1] = (k1 * c + k0 * s) * m;
}

// ---------------- MFMA flash attention (epilogue -> packed ATTN) ----------------
__device__ __forceinline__ void split_store4(float4 v, unsigned short* hi, unsigned short* lo) {
  ushort4 h, l;
  h.x = f2bf_rne(v.x); l.x = f2bf_rne(v.x - __uint_as_float((unsigned)h.x << 16));
  h.y = f2bf_rne(v.y); l.y = f2bf_rne(v.y - __uint_as_float((unsigned)h.y << 16));
  h.z = f2bf_rne(v.z); l.z = f2bf_rne(v.z - __uint_as_float((unsigned)h.z << 16));
  h.w = f2bf_rne(v.w); l.w = f2bf_rne(v.w - __uint_as_float((unsigned)h.w << 16));
  *(ushort4*)hi = h; *(ushort4*)lo = l;
}

__global__ __launch_bounds__(128) void k_attn_mfma(const float* __restrict__ ws_ro, float* __restrict__ wsw) {
  int qt = blockIdx.x % 80;
  int bh = blockIdx.x / 80;
  int b = bh >> 2, h = bh & 3;
  int q0 = qt * 32;
  float scale = (q0 < L_) ? SCALE_ : ws_ro[O_EFF + b];

  const float* Qg = ws_ro + O_Q + ((size_t)bh * T_ + q0) * HD_;
  const float* Kg = ws_ro + O_K + (size_t)bh * T_ * HD_;
  const float* Vg = ws_ro + O_V + (size_t)bh * T_ * HD_;

  __shared__ __align__(16) unsigned short ks_hi[32 * 136];
  __shared__ __align__(16) unsigned short ks_lo[32 * 136];
  __shared__ __align__(16) unsigned short vt_hi[128 * 40];
  __shared__ __align__(16) unsigned short ps[2 * 16 * 40];

  int tid = threadIdx.x;
  int w = tid >> 6, lane = tid & 63;
  int quad = lane >> 4, lc = lane & 15;

  bf16x8 qh[4], ql[4];
  {
    const float* qrowp = Qg + (size_t)(w * 16 + lc) * HD_ + quad * 8;
    #pragma unroll
    for (int k2 = 0; k2 < 4; ++k2) {
      float4 a = *(const float4*)(qrowp + k2 * 32);
      float4 c = *(const float4*)(qrowp + k2 * 32 + 4);
      float v[8] = {a.x, a.y, a.z, a.w, c.x, c.y, c.z, c.w};
      #pragma unroll
      for (int e = 0; e < 8; ++e) {
        float x = v[e] * scale;
        unsigned short hh = f2bf_rne(x);
        float hf = __uint_as_float((unsigned)hh << 16);
        unsigned short ll = f2bf_rne(x - hf);
        qh[k2][e] = (short)hh;
        ql[k2][e] = (short)ll;
      }
    }
  }

  f32x4 o[8];
  #pragma unroll
  for (int i = 0; i < 8; ++i) o[i] = f32x4{0.f, 0.f, 0.f, 0.f};
  float m_r[4] = {-1e30f, -1e30f, -1e30f, -1e30f};
  float l_r[4] = {0.f, 0.f, 0.f, 0.f};

  for (int kt = 0; kt < T_ / 32; ++kt) {
    {
      int row = tid >> 2, f4l = tid & 3;
      const float4* src = (const float4*)(Kg + (size_t)(kt * 32 + row) * HD_);
      #pragma unroll
      for (int i = 0; i < 8; ++i) {
        int f4i = i * 4 + f4l;
        float4 v = src[f4i];
        split_store4(v, &ks_hi[row * 136 + f4i * 4], &ks_lo[row * 136 + f4i * 4]);
      }
    }
    {
      int kp = tid & 15, ch = tid >> 4;
      const float* v0 = Vg + (size_t)(kt * 32 + 2 * kp) * HD_ + ch * 16;
      const float* v1 = v0 + HD_;
      #pragma unroll
      for (int i = 0; i < 4; ++i) {
        float4 x0 = ((const float4*)v0)[i];
        float4 x1 = ((const float4*)v1)[i];
        int d = ch * 16 + i * 4;
        *(unsigned*)&vt_hi[(d + 0) * 40 + 2 * kp] = (unsigned)f2bf_rne(x0.x) | ((unsigned)f2bf_rne(x1.x) << 16);
        *(unsigned*)&vt_hi[(d + 1) * 40 + 2 * kp] = (unsigned)f2bf_rne(x0.y) | ((unsigned)f2bf_rne(x1.y) << 16);
        *(unsigned*)&vt_hi[(d + 2) * 40 + 2 * kp] = (unsigned)f2bf_rne(x0.z) | ((unsigned)f2bf_rne(x1.z) << 16);
        *(unsigned*)&vt_hi[(d + 3) * 40 + 2 * kp] = (unsigned)f2bf_rne(x0.w) | ((unsigned)f2bf_rne(x1.w) << 16);
      }
    }
    __syncthreads();

    f32x4 s0 = {0.f, 0.f, 0.f, 0.f}, s1 = {0.f, 0.f, 0.f, 0.f};
    #pragma unroll
    for (int k2 = 0; k2 < 4; ++k2) {
      int koff = k2 * 32 + quad * 8;
      bf16x8 kh0 = *(const bf16x8*)&ks_hi[lc * 136 + koff];
      bf16x8 kl0 = *(const bf16x8*)&ks_lo[lc * 136 + koff];
      bf16x8 kh1 = *(const bf16x8*)&ks_hi[(lc + 16) * 136 + koff];
      bf16x8 kl1 = *(const bf16x8*)&ks_lo[(lc + 16) * 136 + koff];
      s0 = __builtin_amdgcn_mfma_f32_16x16x32_bf16(ql[k2], kh0, s0, 0, 0, 0);
      s0 = __builtin_amdgcn_mfma_f32_16x16x32_bf16(qh[k2], kl0, s0, 0, 0, 0);
      s0 = __builtin_amdgcn_mfma_f32_16x16x32_bf16(qh[k2], kh0, s0, 0, 0, 0);
      s1 = __builtin_amdgcn_mfma_f32_16x16x32_bf16(ql[k2], kh1, s1, 0, 0, 0);
      s1 = __builtin_amdgcn_mfma_f32_16x16x32_bf16(qh[k2], kl1, s1, 0, 0, 0);
      s1 = __builtin_amdgcn_mfma_f32_16x16x32_bf16(qh[k2], kh1, s1, 0, 0, 0);
    }

    float alpha[4];
    #pragma unroll
    for (int r = 0; r < 4; ++r) {
      float rm = fmaxf(s0[r], s1[r]);
      rm = fmaxf(rm, __shfl_xor(rm, 1, 64));
      rm = fmaxf(rm, __shfl_xor(rm, 2, 64));
      rm = fmaxf(rm, __shfl_xor(rm, 4, 64));
      rm = fmaxf(rm, __shfl_xor(rm, 8, 64));
      float mn = fmaxf(m_r[r], rm);
      alpha[r] = __expf(m_r[r] - mn);
      m_r[r] = mn;
      float p0 = __expf(s0[r] - mn);
      float p1 = __expf(s1[r] - mn);
      float rs = p0 + p1;
      rs += __shfl_xor(rs, 1, 64);
      rs += __shfl_xor(rs, 2, 64);
      rs += __shfl_xor(rs, 4, 64);
      rs += __shfl_xor(rs, 8, 64);
      l_r[r] = l_r[r] * alpha[r] + rs;
      int prow = quad * 4 + r;
      ps[w * 640 + prow * 40 + lc]      = f2bf_rne(p0);
      ps[w * 640 + prow * 40 + lc + 16] = f2bf_rne(p1);
    }
    #pragma unroll
    for (int dt = 0; dt < 8; ++dt) {
      #pragma unroll
      for (int r = 0; r < 4; ++r) o[dt][r] *= alpha[r];
    }

    bf16x8 pa = *(const bf16x8*)&ps[w * 640 + lc * 40 + quad * 8];
    #pragma unroll
    for (int dt = 0; dt < 8; ++dt) {
      bf16x8 vb = *(const bf16x8*)&vt_hi[(dt * 16 + lc) * 40 + quad * 8];
      o[dt] = __builtin_amdgcn_mfma_f32_16x16x32_bf16(pa, vb, o[dt], 0, 0, 0);
    }
    __syncthreads();
  }

  // ---- normalize + pack hi/lo into ATTN [b][t][h*128+d] ----
  unsigned* ATp = (unsigned*)(wsw + O_ATTN);
  int trow0 = q0 + w * 16 + quad * 4;
  #pragma unroll
  for (int r = 0; r < 4; ++r) {
    float inv = 1.0f / l_r[r];
    size_t base = ((size_t)b * T_ + (trow0 + r)) * D_ + h * HD_ + lc;
    #pragma unroll
    for (int dt = 0; dt < 8; ++dt)
      ATp[base + dt * 16] = packhl(o[dt][r] * inv);
  }
}

extern "C" void kernel_launch(void* const* d_in, const int* in_sizes, int n_in,
                              void* d_out, int out_size, void* d_ws, size_t ws_size,
                              hipStream_t stream) {
  (void)in_sizes; (void)n_in; (void)out_size; (void)ws_size;
  const float* txt    = (const float*)d_in[0];
  const float* img    = (const float*)d_in[1];
  const float* vec    = (const float*)d_in[2];
  const float* rope   = (const float*)d_in[3];
  const float* stemp  = (const float*)d_in[4];
  const float* sspat  = (const float*)d_in[5];
  const float* i_aw   = (const float*)d_in[6];
  const float* i_ab   = (const float*)d_in[7];
  const float* i_anw  = (const float*)d_in[8];
  const float* t_aw   = (const float*)d_in[9];
  const float* t_ab   = (const float*)d_in[10];
  const float* t_anw  = (const float*)d_in[11];
  const float* t_qkvw = (const float*)d_in[12];
  const float* i_qkvw = (const float*)d_in[13];
  const float* t_outw = (const float*)d_in[14];
  const float* i_outw = (const float*)d_in[15];
  const float* modw   = (const float*)d_in[16];
  const float* modb   = (const float*)d_in[17];
  const float* i_n2w  = (const float*)d_in[18];
  const float* t_n2w  = (const float*)d_in[19];
  const float* i_f1w  = (const float*)d_in[20];
  const float* i_f1b  = (const float*)d_in[21];
  const float* i_f2w  = (const float*)d_in[22];
  const float* i_f2b  = (const float*)d_in[23];
  const float* t_f1w  = (const float*)d_in[24];
  const float* t_f1b  = (const float*)d_in[25];
  const float* t_f2w  = (const float*)d_in[26];
  const float* t_f2b  = (const float*)d_in[27];
  float* ws = (float*)d_ws;
  float* out = (float*)d_out;
  unsigned* XNp   = (unsigned*)(ws + O_XN);
  unsigned* ATTNp = (unsigned*)(ws + O_ATTN);
  unsigned* XIN2p = (unsigned*)(ws + O_XIN2);
  unsigned* Hpp   = (unsigned*)(ws + O_H);

  hipLaunchKernelGGL(k_adaln, dim3(48), dim3(256), 0, stream, vec, t_aw, t_ab, i_aw, i_ab, ws);
  hipLaunchKernelGGL(k_mod, dim3(64), dim3(256), 0, stream, sspat, modw, modb, stemp, ws);
  hipLaunchKernelGGL((k_rmsmod<true>), dim3(MROWS), dim3(256), 0, stream,
                     txt, img, (const float*)nullptr, t_anw, i_anw, 0, 512, ws, XNp);
  // QKV: N=1536, 3-term, K=512
  hipLaunchKernelGGL((k_gemm<128, 3, 512, 12, 0>), dim3(40 * 12), dim3(256), 0, stream,
                     XNp, t_qkvw, i_qkvw, nullptr, nullptr, ws, ws, txt, img, nullptr, nullptr);
  hipLaunchKernelGGL(k_ropemod, dim3(4096), dim3(256), 0, stream, ws, rope);
  hipLaunchKernelGGL(k_attn_mfma, dim3(640), dim3(128), 0, stream, ws, ws);
  // proj: N=512, 2-term, K=512
  hipLaunchKernelGGL((k_gemm<64, 2, 512, 8, 1>), dim3(40 * 8), dim3(256), 0, stream,
                     ATTNp, t_outw, i_outw, nullptr, nullptr, ws, ws, txt, img, nullptr, nullptr);
  hipLaunchKernelGGL((k_rmsmod<false>), dim3(MROWS), dim3(256), 0, stream,
                     (const float*)nullptr, (const float*)nullptr, ws + O_X2, t_n2w, i_n2w,
                     1536, 2048, ws, XIN2p);
  // fc1: N=2048, 2-term, K=512
  hipLaunchKernelGGL((k_gemm<128, 2, 512, 16, 2>), dim3(40 * 16), dim3(256), 0, stream,
                     XIN2p, t_f1w, i_f1w, t_f1b, i_f1b, ws, ws, txt, img, Hpp, nullptr);
  // fc2: N=512, 2-term, K=2048
  hipLaunchKernelGGL((k_gemm<64, 2, 2048, 8, 3>), dim3(40 * 8), dim3(256), 0, stream,
                     Hpp, t_f2w, i_f2w, t_f2b, i_f2b, ws, ws, txt, img, nullptr, out);
}

// Round 6
// 592.886 us; speedup vs baseline: 3.2445x; 1.1197x over previous
//
#include <hip/hip_runtime.h>
#include <math.h>

// Problem constants (fixed shapes from setup_inputs)
constexpr int B_  = 2;
constexpr int L_  = 512;    // txt tokens
constexpr int N_  = 2048;   // img tokens (H=64, W=32)
constexpr int T_  = 2560;   // L_+N_
constexpr int D_  = 512;
constexpr int NH_ = 4;
constexpr int HD_ = 128;
constexpr int FF_ = 2048;
constexpr int SIXD = 3072;
constexpr int MROWS = B_ * T_;   // 5120
#define SCALE_ 0.08838834764831843f

// Workspace layout (floats). Packed hi/lo activations reuse the same regions.
constexpr size_t QSZ    = (size_t)B_ * NH_ * T_ * HD_;      // 2,621,440 (== B*T*D)
constexpr size_t O_ETXT = 0;
constexpr size_t O_EIMG = O_ETXT + (size_t)B_ * SIXD;       // 6144
constexpr size_t O_MOD  = O_EIMG + (size_t)B_ * SIXD;       // 12288
constexpr size_t O_EFF  = O_MOD + (size_t)B_ * NH_ * N_;    // 28672
constexpr size_t O_XN   = O_EFF + 16;                        // packed u32 [5120][512]
constexpr size_t O_Q    = O_XN + QSZ;                        // f32 Q (rope+mod applied in place)
constexpr size_t O_K    = O_Q + QSZ;                         // f32 K (pre-prep)
constexpr size_t O_V    = O_K + QSZ;                         // f32 V
constexpr size_t O_ATTN = O_V + QSZ;                         // packed u32 [5120][512]
constexpr size_t O_X2   = O_ATTN + QSZ;                      // f32 X2 (after proj); Vt bf16 during attn
constexpr size_t O_XIN2 = O_X2 + QSZ;                        // packed xin2 (after rmsmod2); Kh/Kl bf16 during attn
constexpr size_t O_H    = O_Q;   // packed u32 [5120][2048] over Q..ATTN span (4*QSZ)

typedef short bf16x8 __attribute__((ext_vector_type(8)));
typedef float f32x4 __attribute__((ext_vector_type(4)));

__device__ __forceinline__ unsigned short f2bf_rne(float x) {
  unsigned u = __float_as_uint(x);
  u += 0x7fff + ((u >> 16) & 1);
  return (unsigned short)(u >> 16);
}
// pack f32 -> (hi bf16 << 16) | lo bf16
__device__ __forceinline__ unsigned packhl(float x) {
  unsigned short h = f2bf_rne(x);
  float lof = x - __uint_as_float((unsigned)h << 16);
  unsigned short l = f2bf_rne(lof);
  return ((unsigned)h << 16) | (unsigned)l;
}

// ---------------- adaLN: e = silu(vec) @ W.T + b  (both streams) ----------------
__global__ __launch_bounds__(256) void k_adaln(const float* __restrict__ vec,
                                               const float* __restrict__ wt, const float* __restrict__ bt,
                                               const float* __restrict__ wi, const float* __restrict__ bi,
                                               float* __restrict__ ws) {
  int blk = blockIdx.x;
  int s = blk / (B_ * 12);
  int rem = blk % (B_ * 12);
  int b = rem / 12;
  int o = (rem % 12) * 256 + threadIdx.x;
  __shared__ float sv[D_];
  for (int i = threadIdx.x; i < D_; i += 256) {
    float x = vec[b * D_ + i];
    sv[i] = x / (1.0f + __expf(-x));
  }
  __syncthreads();
  const float* w = (s == 0) ? wt : wi;
  const float* bb = (s == 0) ? bt : bi;
  const float4* wrow = (const float4*)(w + (size_t)o * D_);
  float acc = 0.f;
  for (int d4 = 0; d4 < D_ / 4; ++d4) {
    float4 wv = wrow[d4];
    int d = d4 * 4;
    acc += wv.x * sv[d] + wv.y * sv[d + 1] + wv.z * sv[d + 2] + wv.w * sv[d + 3];
  }
  acc += bb[o];
  float* e = ws + ((s == 0) ? O_ETXT : O_EIMG);
  e[b * SIXD + o] = acc;
}

// ---------------- mod (bilinear upsample + affine + clip + exp) and eff ----------------
__global__ __launch_bounds__(256) void k_mod(const float* __restrict__ sspat,
                                             const float* __restrict__ mw, const float* __restrict__ mb,
                                             const float* __restrict__ stemp,
                                             float* __restrict__ ws) {
  int idx = blockIdx.x * 256 + threadIdx.x;  // B*NH*N = 16384
  if (idx < B_) {
    float s = 0.f;
    for (int h = 0; h < NH_; ++h) s += stemp[idx * NH_ + h];
    float t = fmaxf(s * 0.25f, 0.1f);
    ws[O_EFF + idx] = SCALE_ / t;
  }
  int b = idx / (NH_ * N_);
  int h = (idx / N_) % NH_;
  int n = idx % N_;
  int y = n >> 5;      // W=32
  int x = n & 31;
  float fy = (y + 0.5f) * 0.125f - 0.5f;
  float fx = (x + 0.5f) * 0.25f  - 0.5f;
  float y0f = floorf(fy), x0f = floorf(fx);
  float wy = fy - y0f, wx = fx - x0f;
  int y0 = (int)y0f, x0 = (int)x0f;
  int iy0 = y0 < 0 ? 0 : y0, iy1 = (y0 + 1) > 7 ? 7 : (y0 + 1);
  int ix0 = x0 < 0 ? 0 : x0, ix1 = (x0 + 1) > 7 ? 7 : (x0 + 1);
  const float* S = sspat + b * 64;
  float v00 = S[iy0*8+ix0], v01 = S[iy0*8+ix1];
  float v10 = S[iy1*8+ix0], v11 = S[iy1*8+ix1];
  float up = (1.f-wy)*((1.f-wx)*v00 + wx*v01) + wy*((1.f-wx)*v10 + wx*v11);
  float m = up * mw[h] + mb[h];
  m = fminf(fmaxf(m, -2.f), 2.f);
  ws[O_MOD + idx] = __expf(m);
}

// ---------------- rms + adaLN modulate -> packed hi/lo u32 ----------------
template<bool FROM_INPUT>
__global__ __launch_bounds__(256) void k_rmsmod(const float* __restrict__ txt, const float* __restrict__ img,
                                                const float* __restrict__ src_ws,
                                                const float* __restrict__ nw_txt, const float* __restrict__ nw_img,
                                                int sh_off, int sc_off,
                                                const float* __restrict__ e_ws,
                                                unsigned* __restrict__ outp) {
  int row = blockIdx.x;         // B*T rows
  int b = row / T_;
  int t = row % T_;
  bool is_txt = t < L_;
  int i0 = threadIdx.x * 2;
  float x0, x1;
  if (FROM_INPUT) {
    const float* src = is_txt ? (txt + ((size_t)b * L_ + t) * D_)
                              : (img + ((size_t)b * N_ + (t - L_)) * D_);
    x0 = src[i0]; x1 = src[i0 + 1];
  } else {
    const float* src = src_ws + (size_t)row * D_;
    x0 = src[i0]; x1 = src[i0 + 1];
  }
  float ss = x0 * x0 + x1 * x1;
  for (int off = 32; off; off >>= 1) ss += __shfl_down(ss, off, 64);
  __shared__ float red[4];
  if ((threadIdx.x & 63) == 0) red[threadIdx.x >> 6] = ss;
  __syncthreads();
  float tot = red[0] + red[1] + red[2] + red[3];
  float r = rsqrtf(tot * (1.0f / D_) + 1e-6f);
  const float* e = e_ws + (is_txt ? O_ETXT : O_EIMG) + (size_t)b * SIXD;
  const float* nw = is_txt ? nw_txt : nw_img;
  float y0 = x0 * r * nw[i0]     * (1.f + e[sc_off + i0])     + e[sh_off + i0];
  float y1 = x1 * r * nw[i0 + 1] * (1.f + e[sc_off + i0 + 1]) + e[sh_off + i0 + 1];
  uint2 pk; pk.x = packhl(y0); pk.y = packhl(y1);
  *(uint2*)&outp[(size_t)row * D_ + i0] = pk;
}

// ---------------- templated MFMA GEMM (unchanged) ----------------
template<int NTILE, int NTERMS, int KDIM, int NPR, int EPI>
__global__ __launch_bounds__(256) void k_gemm(
    const unsigned* __restrict__ Ap,
    const float* __restrict__ Wt, const float* __restrict__ Wi,
    const float* __restrict__ biast, const float* __restrict__ biasi,
    const float* __restrict__ ws_ro, float* __restrict__ wsw,
    const float* __restrict__ txt, const float* __restrict__ img,
    unsigned* __restrict__ Hp, float* __restrict__ outf) {
  int mt = blockIdx.x / NPR, nt = blockIdx.x % NPR;
  int row0 = mt * 128;
  int col0 = nt * NTILE;
  int b = row0 / T_;
  int t0 = row0 % T_;
  bool is_txt = t0 < L_;
  const float* W = is_txt ? Wt : Wi;

  __shared__ __align__(16) unsigned short ash[128 * 40];
  __shared__ __align__(16) unsigned short asl[128 * 40];
  __shared__ __align__(16) unsigned short bsh[NTILE * 40];
  __shared__ __align__(16) unsigned short bsl[(NTERMS == 3) ? NTILE * 40 : 8];

  int tid = threadIdx.x;
  int w = tid >> 6, lane = tid & 63, quad = lane >> 4, lc = lane & 15;
  int rh = w >> 1, ch = w & 1;
  constexpr int NFR = NTILE / 32;

  f32x4 acc[4][NFR];
  #pragma unroll
  for (int m = 0; m < 4; ++m)
    #pragma unroll
    for (int n = 0; n < NFR; ++n) acc[m][n] = f32x4{0.f, 0.f, 0.f, 0.f};

  for (int kt = 0; kt < KDIM / 32; ++kt) {
    {
      int r = tid >> 1, koff = (tid & 1) * 16;
      const unsigned* src = Ap + (size_t)(row0 + r) * KDIM + kt * 32 + koff;
      unsigned pw[16];
      *(uint4*)&pw[0]  = ((const uint4*)src)[0];
      *(uint4*)&pw[4]  = ((const uint4*)src)[1];
      *(uint4*)&pw[8]  = ((const uint4*)src)[2];
      *(uint4*)&pw[12] = ((const uint4*)src)[3];
      unsigned hw[8], lw[8];
      #pragma unroll
      for (int e2 = 0; e2 < 8; ++e2) {
        unsigned x = pw[2 * e2], y = pw[2 * e2 + 1];
        hw[e2] = (x >> 16) | (y & 0xffff0000u);
        lw[e2] = (x & 0xffffu) | (y << 16);
      }
      *(uint4*)&ash[r * 40 + koff]     = *(uint4*)&hw[0];
      *(uint4*)&ash[r * 40 + koff + 8] = *(uint4*)&hw[4];
      *(uint4*)&asl[r * 40 + koff]     = *(uint4*)&lw[0];
      *(uint4*)&asl[r * 40 + koff + 8] = *(uint4*)&lw[4];
    }
    {
      constexpr int NW = NTILE * 8 / 256;
      #pragma unroll
      for (int wc = 0; wc < NW; ++wc) {
        int idx = wc * 256 + tid;
        int rw = idx >> 3, c4 = idx & 7;
        float4 v = *(const float4*)(W + (size_t)(col0 + rw) * KDIM + kt * 32 + c4 * 4);
        ushort4 hh;
        hh.x = f2bf_rne(v.x); hh.y = f2bf_rne(v.y); hh.z = f2bf_rne(v.z); hh.w = f2bf_rne(v.w);
        *(ushort4*)&bsh[rw * 40 + c4 * 4] = hh;
        if (NTERMS == 3) {
          ushort4 ll;
          ll.x = f2bf_rne(v.x - __uint_as_float((unsigned)hh.x << 16));
          ll.y = f2bf_rne(v.y - __uint_as_float((unsigned)hh.y << 16));
          ll.z = f2bf_rne(v.z - __uint_as_float((unsigned)hh.z << 16));
          ll.w = f2bf_rne(v.w - __uint_as_float((unsigned)hh.w << 16));
          *(ushort4*)&bsl[rw * 40 + c4 * 4] = ll;
        }
      }
    }
    __syncthreads();

    bf16x8 afh[4], afl[4];
    #pragma unroll
    for (int m = 0; m < 4; ++m) {
      int ar = rh * 64 + m * 16 + lc;
      afh[m] = *(const bf16x8*)&ash[ar * 40 + quad * 8];
      afl[m] = *(const bf16x8*)&asl[ar * 40 + quad * 8];
    }
    #pragma unroll
    for (int n = 0; n < NFR; ++n) {
      int br = ch * (NTILE / 2) + n * 16 + lc;
      bf16x8 bh = *(const bf16x8*)&bsh[br * 40 + quad * 8];
      if (NTERMS == 3) {
        bf16x8 bl = *(const bf16x8*)&bsl[br * 40 + quad * 8];
        #pragma unroll
        for (int m = 0; m < 4; ++m) {
          acc[m][n] = __builtin_amdgcn_mfma_f32_16x16x32_bf16(afl[m], bh, acc[m][n], 0, 0, 0);
          acc[m][n] = __builtin_amdgcn_mfma_f32_16x16x32_bf16(afh[m], bl, acc[m][n], 0, 0, 0);
          acc[m][n] = __builtin_amdgcn_mfma_f32_16x16x32_bf16(afh[m], bh, acc[m][n], 0, 0, 0);
        }
      } else {
        #pragma unroll
        for (int m = 0; m < 4; ++m) {
          acc[m][n] = __builtin_amdgcn_mfma_f32_16x16x32_bf16(afl[m], bh, acc[m][n], 0, 0, 0);
          acc[m][n] = __builtin_amdgcn_mfma_f32_16x16x32_bf16(afh[m], bh, acc[m][n], 0, 0, 0);
        }
      }
    }
    __syncthreads();
  }

  const float* e = ws_ro + (is_txt ? O_ETXT : O_EIMG) + (size_t)b * SIXD;
  const float* bias = is_txt ? biast : biasi;
  #pragma unroll
  for (int m = 0; m < 4; ++m) {
    #pragma unroll
    for (int n = 0; n < NFR; ++n) {
      #pragma unroll
      for (int r = 0; r < 4; ++r) {
        int rg = row0 + rh * 64 + m * 16 + quad * 4 + r;
        int cg = col0 + ch * (NTILE / 2) + n * 16 + lc;
        float val = acc[m][n][r];
        int tt = rg % T_;
        if (EPI == 0) {
          int which = cg >> 9, h = (cg >> 7) & 3, dd = cg & 127;
          float* dst = wsw + (which == 0 ? O_Q : which == 1 ? O_K : O_V)
                     + (((size_t)b * NH_ + h) * T_ + tt) * HD_ + dd;
          *dst = val;
        } else if (EPI == 1) {
          float g = e[1024 + cg];
          float res = is_txt ? txt[((size_t)b * L_ + tt) * D_ + cg]
                             : img[((size_t)b * N_ + (tt - L_)) * D_ + cg];
          wsw[O_X2 + (size_t)rg * D_ + cg] = res + g * val;
        } else if (EPI == 2) {
          float x = val + bias[cg];
          float z = 0.7978845608028654f * (x + 0.044715f * x * x * x);
          z = fminf(fmaxf(z, -40.f), 40.f);
          float u = __expf(-2.f * z);
          float th = (1.f - u) / (1.f + u);
          Hp[(size_t)rg * FF_ + cg] = packhl(0.5f * x * (1.f + th));
        } else {
          float g = e[2560 + cg];
          float v2 = ws_ro[O_X2 + (size_t)rg * D_ + cg] + g * (val + bias[cg]);
          size_t oi = is_txt ? ((size_t)b * L_ + tt) * D_ + cg
                             : (size_t)B_ * L_ * D_ + ((size_t)b * N_ + (tt - L_)) * D_ + cg;
          outf[oi] = v2;
        }
      }
    }
  }
}

// ---------------- prep: rope+mod on Q (in place f32), K -> pre-split bf16 hi/lo ----------------
__global__ __launch_bounds__(256) void k_prep(float* __restrict__ wsw, const float* __restrict__ rope) {
  int idx = blockIdx.x * 256 + threadIdx.x;  // B*NH*T*64 = 1,310,720
  int i = idx & 63;
  int p = idx >> 6;                 // bh*T + t
  int t = p % T_;
  int bh = p / T_;
  size_t base = (size_t)p * HD_ + 2 * i;
  float* Q = wsw + O_Q;
  float* K = wsw + O_K;
  float k0 = K[base], k1 = K[base + 1];
  if (t >= L_) {
    int n = t - L_;
    float c = rope[(size_t)n * HD_ + 2 * i];
    float s = rope[(size_t)n * HD_ + 2 * i + 1];
    float m = wsw[O_MOD + (size_t)bh * N_ + n];
    float q0 = Q[base], q1 = Q[base + 1];
    Q[base]     = (q0 * c - q1 * s) * m;
    Q[base + 1] = (q1 * c + q0 * s) * m;
    float nk0 = (k0 * c - k1 * s) * m;
    float nk1 = (k1 * c + k0 * s) * m;
    k0 = nk0; k1 = nk1;
  }
  unsigned short h0 = f2bf_rne(k0), h1 = f2bf_rne(k1);
  unsigned short l0 = f2bf_rne(k0 - __uint_as_float((unsigned)h0 << 16));
  unsigned short l1 = f2bf_rne(k1 - __uint_as_float((unsigned)h1 << 16));
  unsigned* KH32 = (unsigned*)(wsw + O_XIN2);
  unsigned* KL32 = KH32 + QSZ / 2;
  KH32[(size_t)p * 64 + i] = (unsigned)h0 | ((unsigned)h1 << 16);
  KL32[(size_t)p * 64 + i] = (unsigned)l0 | ((unsigned)l1 << 16);
}

// ---------------- V f32 [bh][t][128] -> Vt bf16 [bh][d][T] (tiled transpose) ----------------
__global__ __launch_bounds__(256) void k_vt(const float* __restrict__ ws_ro, float* __restrict__ wsw) {
  int bh = blockIdx.x & 7;
  int tt = blockIdx.x >> 3;      // 0..39
  int t0 = tt * 64;
  __shared__ unsigned short vls[128 * 72];
  int tid = threadIdx.x;
  {
    int tr = tid & 63, dc = tid >> 6;  // dc: 0..3 (32-d chunk)
    const float4* src = (const float4*)(ws_ro + O_V + ((size_t)bh * T_ + t0 + tr) * HD_ + dc * 32);
    #pragma unroll
    for (int f = 0; f < 8; ++f) {
      float4 v = src[f];
      int d = dc * 32 + f * 4;
      vls[(d + 0) * 72 + tr] = f2bf_rne(v.x);
      vls[(d + 1) * 72 + tr] = f2bf_rne(v.y);
      vls[(d + 2) * 72 + tr] = f2bf_rne(v.z);
      vls[(d + 3) * 72 + tr] = f2bf_rne(v.w);
    }
  }
  __syncthreads();
  {
    int d = tid >> 1, th = (tid & 1) * 32;
    unsigned* Vt32 = (unsigned*)(wsw + O_X2);
    size_t obase = (((size_t)bh * HD_ + d) * T_ + t0 + th) >> 1;
    #pragma unroll
    for (int k = 0; k < 16; ++k) {
      unsigned lo = vls[d * 72 + th + 2 * k];
      unsigned hi = vls[d * 72 + th + 2 * k + 1];
      Vt32[obase + k] = lo | (hi << 16);
    }
  }
}

// ---------------- MFMA flash attention v3 (staging fixed: full tiles) ----------------
__global__ __launch_bounds__(256) void k_attn3(const float* __restrict__ ws_ro, float* __restrict__ wsw) {
  int bh = blockIdx.x & 7;            // bh-per-XCD swizzle for L2 locality
  int qg = blockIdx.x >> 3;           // 0..39
  int b = bh >> 2, h = bh & 3;
  int tid = threadIdx.x;
  int w = tid >> 6, lane = tid & 63, quad = lane >> 4, lc = lane & 15;
  int q0 = (qg * 4 + w) * 16;
  float scale = (q0 < L_) ? SCALE_ : ws_ro[O_EFF + b];

  const unsigned short* Khs = (const unsigned short*)(ws_ro + O_XIN2);
  const unsigned short* Kls = Khs + QSZ;
  const unsigned short* Vts = (const unsigned short*)(ws_ro + O_X2);

  __shared__ __align__(16) unsigned short ksh[64 * 136];
  __shared__ __align__(16) unsigned short ksl[64 * 136];
  __shared__ __align__(16) unsigned short vts[128 * 72];
  __shared__ __align__(16) unsigned short ps[4 * 16 * 72];

  // ---- Q frags direct from global f32 (scaled + hi/lo split, once) ----
  bf16x8 qh[4], ql[4];
  {
    const float* qrowp = ws_ro + O_Q + ((size_t)bh * T_ + q0 + lc) * HD_ + quad * 8;
    #pragma unroll
    for (int k2 = 0; k2 < 4; ++k2) {
      float4 a = *(const float4*)(qrowp + k2 * 32);
      float4 c = *(const float4*)(qrowp + k2 * 32 + 4);
      float v[8] = {a.x, a.y, a.z, a.w, c.x, c.y, c.z, c.w};
      #pragma unroll
      for (int e = 0; e < 8; ++e) {
        float x = v[e] * scale;
        unsigned short hh = f2bf_rne(x);
        float hf = __uint_as_float((unsigned)hh << 16);
        qh[k2][e] = (short)hh;
        ql[k2][e] = (short)f2bf_rne(x - hf);
      }
    }
  }

  f32x4 o[8];
  #pragma unroll
  for (int i = 0; i < 8; ++i) o[i] = f32x4{0.f, 0.f, 0.f, 0.f};
  float m_r[4] = {-1e30f, -1e30f, -1e30f, -1e30f};
  float l_r[4] = {0.f, 0.f, 0.f, 0.f};

  for (int kt = 0; kt < T_ / 64; ++kt) {
    // ---- stage K hi/lo (64 rows x 128) + Vt (128 rows x 64) — full tiles ----
    {
      int row = tid >> 2, cs = tid & 3;
      size_t gbase = ((size_t)bh * T_ + kt * 64 + row) * HD_;
      #pragma unroll
      for (int cc = 0; cc < 4; ++cc) {
        int c = cs + cc * 4;                 // 0..15: 16 uint4 = 128 ushorts
        *(uint4*)&ksh[row * 136 + c * 8] = *(const uint4*)&Khs[gbase + c * 8];
        *(uint4*)&ksl[row * 136 + c * 8] = *(const uint4*)&Kls[gbase + c * 8];
      }
      int d = tid >> 1, vc = tid & 1;
      size_t vbase = ((size_t)bh * HD_ + d) * T_ + kt * 64;
      #pragma unroll
      for (int cc = 0; cc < 4; ++cc) {
        int c = vc + cc * 2;                 // 0..7: 8 uint4 = 64 ushorts
        *(uint4*)&vts[d * 72 + c * 8] = *(const uint4*)&Vts[vbase + c * 8];
      }
    }
    __syncthreads();

    // ---- S = Q K^T (3-term hi/lo), 4 x 16-key n-tiles ----
    f32x4 s[4];
    #pragma unroll
    for (int nt = 0; nt < 4; ++nt) s[nt] = f32x4{0.f, 0.f, 0.f, 0.f};
    #pragma unroll
    for (int k2 = 0; k2 < 4; ++k2) {
      int ko = k2 * 32 + quad * 8;
      #pragma unroll
      for (int nt = 0; nt < 4; ++nt) {
        bf16x8 kh = *(const bf16x8*)&ksh[(nt * 16 + lc) * 136 + ko];
        bf16x8 kl = *(const bf16x8*)&ksl[(nt * 16 + lc) * 136 + ko];
        s[nt] = __builtin_amdgcn_mfma_f32_16x16x32_bf16(ql[k2], kh, s[nt], 0, 0, 0);
        s[nt] = __builtin_amdgcn_mfma_f32_16x16x32_bf16(qh[k2], kl, s[nt], 0, 0, 0);
        s[nt] = __builtin_amdgcn_mfma_f32_16x16x32_bf16(qh[k2], kh, s[nt], 0, 0, 0);
      }
    }

    // ---- online softmax over 64 keys ----
    float alpha[4];
    unsigned short* pw = &ps[w * 1152];
    #pragma unroll
    for (int r = 0; r < 4; ++r) {
      float rm = fmaxf(fmaxf(s[0][r], s[1][r]), fmaxf(s[2][r], s[3][r]));
      rm = fmaxf(rm, __shfl_xor(rm, 1, 64));
      rm = fmaxf(rm, __shfl_xor(rm, 2, 64));
      rm = fmaxf(rm, __shfl_xor(rm, 4, 64));
      rm = fmaxf(rm, __shfl_xor(rm, 8, 64));
      float mn = fmaxf(m_r[r], rm);
      alpha[r] = __expf(m_r[r] - mn);
      m_r[r] = mn;
      float p0 = __expf(s[0][r] - mn);
      float p1 = __expf(s[1][r] - mn);
      float p2 = __expf(s[2][r] - mn);
      float p3 = __expf(s[3][r] - mn);
      float rs = (p0 + p1) + (p2 + p3);
      rs += __shfl_xor(rs, 1, 64);
      rs += __shfl_xor(rs, 2, 64);
      rs += __shfl_xor(rs, 4, 64);
      rs += __shfl_xor(rs, 8, 64);
      l_r[r] = l_r[r] * alpha[r] + rs;
      int prow = quad * 4 + r;
      pw[prow * 72 + lc]      = f2bf_rne(p0);
      pw[prow * 72 + lc + 16] = f2bf_rne(p1);
      pw[prow * 72 + lc + 32] = f2bf_rne(p2);
      pw[prow * 72 + lc + 48] = f2bf_rne(p3);
    }
    #pragma unroll
    for (int dt = 0; dt < 8; ++dt) {
      #pragma unroll
      for (int r = 0; r < 4; ++r) o[dt][r] *= alpha[r];
    }

    // ---- O += P V  (A from wave-private ps, B from vts) ----
    bf16x8 pa0 = *(const bf16x8*)&pw[lc * 72 + quad * 8];
    bf16x8 pa1 = *(const bf16x8*)&pw[lc * 72 + 32 + quad * 8];
    #pragma unroll
    for (int dt = 0; dt < 8; ++dt) {
      bf16x8 vb0 = *(const bf16x8*)&vts[(dt * 16 + lc) * 72 + quad * 8];
      bf16x8 vb1 = *(const bf16x8*)&vts[(dt * 16 + lc) * 72 + 32 + quad * 8];
      o[dt] = __builtin_amdgcn_mfma_f32_16x16x32_bf16(pa0, vb0, o[dt], 0, 0, 0);
      o[dt] = __builtin_amdgcn_mfma_f32_16x16x32_bf16(pa1, vb1, o[dt], 0, 0, 0);
    }
    __syncthreads();
  }

  // ---- normalize + pack hi/lo into ATTN [b][t][h*128+d] ----
  unsigned* ATp = (unsigned*)(wsw + O_ATTN);
  int trow0 = q0 + quad * 4;
  #pragma unroll
  for (int r = 0; r < 4; ++r) {
    float inv = 1.0f / l_r[r];
    size_t base = ((size_t)b * T_ + (trow0 + r)) * D_ + h * HD_ + lc;
    #pragma unroll
    for (int dt = 0; dt < 8; ++dt)
      ATp[base + dt * 16] = packhl(o[dt][r] * inv);
  }
}

extern "C" void kernel_launch(void* const* d_in, const int* in_sizes, int n_in,
                              void* d_out, int out_size, void* d_ws, size_t ws_size,
                              hipStream_t stream) {
  (void)in_sizes; (void)n_in; (void)out_size; (void)ws_size;
  const float* txt    = (const float*)d_in[0];
  const float* img    = (const float*)d_in[1];
  const float* vec    = (const float*)d_in[2];
  const float* rope   = (const float*)d_in[3];
  const float* stemp  = (const float*)d_in[4];
  const float* sspat  = (const float*)d_in[5];
  const float* i_aw   = (const float*)d_in[6];
  const float* i_ab   = (const float*)d_in[7];
  const float* i_anw  = (const float*)d_in[8];
  const float* t_aw   = (const float*)d_in[9];
  const float* t_ab   = (const float*)d_in[10];
  const float* t_anw  = (const float*)d_in[11];
  const float* t_qkvw = (const float*)d_in[12];
  const float* i_qkvw = (const float*)d_in[13];
  const float* t_outw = (const float*)d_in[14];
  const float* i_outw = (const float*)d_in[15];
  const float* modw   = (const float*)d_in[16];
  const float* modb   = (const float*)d_in[17];
  const float* i_n2w  = (const float*)d_in[18];
  const float* t_n2w  = (const float*)d_in[19];
  const float* i_f1w  = (const float*)d_in[20];
  const float* i_f1b  = (const float*)d_in[21];
  const float* i_f2w  = (const float*)d_in[22];
  const float* i_f2b  = (const float*)d_in[23];
  const float* t_f1w  = (const float*)d_in[24];
  const float* t_f1b  = (const float*)d_in[25];
  const float* t_f2w  = (const float*)d_in[26];
  const float* t_f2b  = (const float*)d_in[27];
  float* ws = (float*)d_ws;
  float* out = (float*)d_out;
  unsigned* XNp   = (unsigned*)(ws + O_XN);
  unsigned* ATTNp = (unsigned*)(ws + O_ATTN);
  unsigned* XIN2p = (unsigned*)(ws + O_XIN2);
  unsigned* Hpp   = (unsigned*)(ws + O_H);

  hipLaunchKernelGGL(k_adaln, dim3(48), dim3(256), 0, stream, vec, t_aw, t_ab, i_aw, i_ab, ws);
  hipLaunchKernelGGL(k_mod, dim3(64), dim3(256), 0, stream, sspat, modw, modb, stemp, ws);
  hipLaunchKernelGGL((k_rmsmod<true>), dim3(MROWS), dim3(256), 0, stream,
                     txt, img, (const float*)nullptr, t_anw, i_anw, 0, 512, ws, XNp);
  // QKV: N=1536, 3-term, K=512
  hipLaunchKernelGGL((k_gemm<128, 3, 512, 12, 0>), dim3(40 * 12), dim3(256), 0, stream,
                     XNp, t_qkvw, i_qkvw, nullptr, nullptr, ws, ws, txt, img, nullptr, nullptr);
  hipLaunchKernelGGL(k_prep, dim3(5120), dim3(256), 0, stream, ws, rope);
  hipLaunchKernelGGL(k_vt, dim3(320), dim3(256), 0, stream, ws, ws);
  hipLaunchKernelGGL(k_attn3, dim3(320), dim3(256), 0, stream, ws, ws);
  // proj: N=512, 2-term, K=512
  hipLaunchKernelGGL((k_gemm<64, 2, 512, 8, 1>), dim3(40 * 8), dim3(256), 0, stream,
                     ATTNp, t_outw, i_outw, nullptr, nullptr, ws, ws, txt, img, nullptr, nullptr);
  hipLaunchKernelGGL((k_rmsmod<false>), dim3(MROWS), dim3(256), 0, stream,
                     (const float*)nullptr, (const float*)nullptr, ws + O_X2, t_n2w, i_n2w,
                     1536, 2048, ws, XIN2p);
  // fc1: N=2048, 2-term, K=512
  hipLaunchKernelGGL((k_gemm<128, 2, 512, 16, 2>), dim3(40 * 16), dim3(256), 0, stream,
                     XIN2p, t_f1w, i_f1w, t_f1b, i_f1b, ws, ws, txt, img, Hpp, nullptr);
  // fc2: N=512, 2-term, K=2048
  hipLaunchKernelGGL((k_gemm<64, 2, 2048, 8, 3>), dim3(40 * 8), dim3(256), 0, stream,
                     Hpp, t_f2w, i_f2w, t_f2b, i_f2b, ws, ws, txt, img, nullptr, out);
}